// Round 3
// baseline (248.339 us; speedup 1.0000x reference)
//
#include <hip/hip_runtime.h>
#include <hip/hip_bf16.h>
#include <cstdint>

typedef __bf16 bf16x8 __attribute__((ext_vector_type(8)));
typedef float f32x4 __attribute__((ext_vector_type(4)));

// ---------------- async global->LDS (16B per lane) ----------------
__device__ __forceinline__ void gld16(const __bf16* g, __bf16* lds) {
    __builtin_amdgcn_global_load_lds(
        (__attribute__((address_space(1))) void*)(uintptr_t)g,
        (__attribute__((address_space(3))) void*)(uint32_t)(uintptr_t)lds,
        16, 0, 0);
}

// ---------------- transpose + f32->bf16 convert: out[C][R] = in[R][C] ----------------
__global__ __launch_bounds__(256) void transpose_bf16_k(const float* __restrict__ in,
                                                        __bf16* __restrict__ out,
                                                        int R, int C) {
    __shared__ float t[64][65];
    const int r0 = blockIdx.x * 64, c0 = blockIdx.y * 64;
    const int tid = threadIdx.x;
#pragma unroll
    for (int i = 0; i < 16; i++) {
        int idx = i * 256 + tid;
        int rr = idx >> 6, cc = idx & 63;
        t[rr][cc] = in[(size_t)(r0 + rr) * C + (c0 + cc)];
    }
    __syncthreads();
#pragma unroll
    for (int i = 0; i < 16; i++) {
        int idx = i * 256 + tid;
        int rr = idx >> 6, cc = idx & 63;
        out[(size_t)(c0 + rr) * R + (r0 + cc)] = (__bf16)t[cc][rr];
    }
}

// ---------------- encoder: per (row, segment) 2-layer MLP ----------------
template <int DIN, int MODE>
__global__ __launch_bounds__(256) void enc_kernel(const float* __restrict__ obs,
                                                  const float* __restrict__ act,
                                                  const float* __restrict__ W1g,
                                                  const float* __restrict__ b1g,
                                                  const float* __restrict__ W2g,
                                                  const float* __restrict__ b2g,
                                                  __bf16* __restrict__ enc,
                                                  int kgBase, int xBase) {
    const int k = blockIdx.y;
    const int kg = kgBase + k;
    __shared__ float sW1[DIN * 32];
    __shared__ float sW2[32 * 64];
    __shared__ float sb1[32];
    __shared__ float sb2[64];
    const int tid = threadIdx.x;
    for (int i = tid; i < DIN * 32; i += 256) sW1[i] = W1g[k * DIN * 32 + i];
    for (int i = tid; i < 2048; i += 256) sW2[i] = W2g[k * 2048 + i];
    if (tid < 32) sb1[tid] = b1g[k * 32 + tid];
    else if (tid < 96) sb2[tid - 32] = b2g[k * 64 + (tid - 32)];
    __syncthreads();

    const int r = blockIdx.x * 256 + tid;
    const float* orow = obs + (size_t)r * 144;
    float x[DIN];
    if (MODE == 0) {
        x[0] = orow[2 * k];
        x[1] = orow[2 * k + 1];
        const float* arow = act + (size_t)r * 3;
        x[2] = arow[0]; x[3] = arow[1]; x[4] = arow[2];
    } else {
#pragma unroll
        for (int i = 0; i < DIN; i++) x[i] = orow[xBase + DIN * k + i];
    }

    float h[32];
#pragma unroll
    for (int o = 0; o < 32; o++) {
        float a = sb1[o];
#pragma unroll
        for (int i = 0; i < DIN; i++) a += x[i] * sW1[i * 32 + o];
        h[o] = fmaxf(a, 0.01f * a);
    }

    __bf16* dst = enc + (size_t)r * 896 + kg * 64;
#pragma unroll
    for (int og = 0; og < 8; og++) {
        bf16x8 tmp;
#pragma unroll
        for (int oi = 0; oi < 8; oi++) {
            const int o = og * 8 + oi;
            float a = sb2[o];
#pragma unroll
            for (int hh = 0; hh < 32; hh++) a += h[hh] * sW2[hh * 64 + o];
            a = fmaxf(a, 0.01f * a);
            tmp[oi] = (__bf16)a;
        }
        *(bf16x8*)&dst[og * 8] = tmp;
    }
}

// ---------------- 256x256 4-phase/K-tile bf16 GEMM: C = relu(A @ Bt^T + bias) ----------------
// 8 waves (2M x 4N), BK=64, dbuf 128KiB LDS XOR-swizzled, full next-tile staging in
// phase 1, counted vmcnt (10/8/-/4), dual B register sets, bn-fast XCD-chunk ordering.
__global__ __launch_bounds__(512, 2) void gemm256_relu(const __bf16* __restrict__ Ag,
                                                       const __bf16* __restrict__ Btg,
                                                       const float* __restrict__ bias,
                                                       __bf16* __restrict__ Cg,
                                                       int N, int K, int lgn) {
    // lds[buf][A=0/B=1][half][128*64]
    __shared__ __align__(16) __bf16 lds[2][2][2][128 * 64];
    const int tid = threadIdx.x;
    const int wid = tid >> 6, lane = tid & 63;
    const int wm = wid >> 2, wn = wid & 3;
    const int fr = lane & 15, kq = lane >> 4;

    // XCD-aware swizzle; within each XCD chunk bn varies fastest (same-bm blocks
    // co-resident on one XCD -> A-tile shared in its L2; distinct bm range per XCD).
    const int chunk = gridDim.x >> 3;
    const int wg = (blockIdx.x & 7) * chunk + (blockIdx.x >> 3);
    const int bn = wg & ((1 << lgn) - 1), bm = wg >> lgn;

    // staging: chunk c: row=c>>3, slot=c&7; source slot pre-swizzled by ^(row&7)
    const int c0 = tid, c1 = tid + 512;
    const int r0 = c0 >> 3, s0 = (c0 & 7) ^ (r0 & 7);
    const int r1 = c1 >> 3, s1 = (c1 & 7) ^ (r1 & 7);
    const size_t h128 = (size_t)128 * K;
    const __bf16* aB0 = Ag + (size_t)(bm * 256 + r0) * K + s0 * 8;
    const __bf16* aB1 = Ag + (size_t)(bm * 256 + r1) * K + s1 * 8;
    const __bf16* bB0 = Btg + (size_t)(bn * 256 + r0) * K + s0 * 8;
    const __bf16* bB1 = Btg + (size_t)(bn * 256 + r1) * K + s1 * 8;

    f32x4 acc[2][2][4][2] = {};
    bf16x8 af[4][2], bf0[2][2], bf1[2][2];

#define STAGE(BUF, AB, H, KO)                                         \
    do {                                                              \
        __bf16* d_ = &lds[BUF][AB][H][0];                             \
        const __bf16* g0_ = ((AB) ? bB0 : aB0) + (H) * h128 + (KO);   \
        const __bf16* g1_ = ((AB) ? bB1 : aB1) + (H) * h128 + (KO);   \
        gld16(g0_, d_ + c0 * 8);                                      \
        gld16(g1_, d_ + c1 * 8);                                      \
    } while (0)

    // swizzled fragment read: 8 slots of 16B per 128B row, slot ^= (row&7)
#define LDF(BUF, AB, H, ROW, KS) \
    (*(const bf16x8*)&lds[BUF][AB][H][(ROW) * 64 + (((KS)*4 + kq) ^ ((ROW)&7)) * 8])

#define LOAD_A(BUF, H)                                                \
    _Pragma("unroll") for (int m = 0; m < 4; m++)                     \
        _Pragma("unroll") for (int ks = 0; ks < 2; ks++)              \
            af[m][ks] = LDF(BUF, 0, H, wm * 64 + m * 16 + fr, ks);

#define LOAD_B(BUF, H, DST)                                           \
    _Pragma("unroll") for (int n = 0; n < 2; n++)                     \
        _Pragma("unroll") for (int ks = 0; ks < 2; ks++)              \
            DST[n][ks] = LDF(BUF, 1, H, wn * 32 + n * 16 + fr, ks);

#define MFMA_Q(Q, R, BREG)                                            \
    __builtin_amdgcn_s_barrier();                                     \
    asm volatile("s_waitcnt lgkmcnt(0)" ::: "memory");                \
    __builtin_amdgcn_sched_barrier(0);                                \
    __builtin_amdgcn_s_setprio(1);                                    \
    _Pragma("unroll") for (int ks = 0; ks < 2; ks++)                  \
        _Pragma("unroll") for (int m = 0; m < 4; m++)                 \
            _Pragma("unroll") for (int n = 0; n < 2; n++)             \
                acc[Q][R][m][n] = __builtin_amdgcn_mfma_f32_16x16x32_bf16( \
                    af[m][ks], BREG[n][ks], acc[Q][R][m][n], 0, 0, 0);\
    __builtin_amdgcn_s_setprio(0);

#define VMW(N) asm volatile("s_waitcnt vmcnt(" #N ")" ::: "memory")

    const int NT = K >> 6;

    // prologue: stage tile 0 (queue order A0,B0,B1,A1), full drain once
    STAGE(0, 0, 0, 0);
    STAGE(0, 1, 0, 0);
    STAGE(0, 1, 1, 0);
    STAGE(0, 0, 1, 0);
    VMW(0);
    __builtin_amdgcn_s_barrier();

    for (int t = 0; t < NT - 1; ++t) {
        const int buf = t & 1, nb = buf ^ 1;
        const int kO = (t + 1) << 6;

        // phase 1: Q(0,0); stage ALL of next tile (order A0,B0,B1,A1)
        LOAD_A(buf, 0)
        LOAD_B(buf, 0, bf0)
        STAGE(nb, 0, 0, kO);
        STAGE(nb, 1, 0, kO);
        STAGE(nb, 1, 1, kO);
        STAGE(nb, 0, 1, kO);
        MFMA_Q(0, 0, bf0)
        VMW(10);  // B1(t) landed   [queue: B1,A1 | A0',B0',B1',A1']
        __builtin_amdgcn_s_barrier();

        // phase 2: Q(0,1)
        LOAD_B(buf, 1, bf1)
        MFMA_Q(0, 1, bf1)
        VMW(8);   // A1(t) landed
        __builtin_amdgcn_s_barrier();

        // phase 3: Q(1,1)
        LOAD_A(buf, 1)
        MFMA_Q(1, 1, bf1)
        __builtin_amdgcn_s_barrier();

        // phase 4: Q(1,0) — operands already in regs
        MFMA_Q(1, 0, bf0)
        VMW(4);   // A0,B0 of next tile landed
        __builtin_amdgcn_s_barrier();
    }

    // peeled last tile (nothing staged beyond it)
    {
        const int buf = (NT - 1) & 1;
        LOAD_A(buf, 0)
        LOAD_B(buf, 0, bf0)
        MFMA_Q(0, 0, bf0)
        VMW(2);
        __builtin_amdgcn_s_barrier();
        LOAD_B(buf, 1, bf1)
        MFMA_Q(0, 1, bf1)
        VMW(0);
        __builtin_amdgcn_s_barrier();
        LOAD_A(buf, 1)
        MFMA_Q(1, 1, bf1)
        __builtin_amdgcn_s_barrier();
        MFMA_Q(1, 0, bf0)
    }

    // epilogue: C/D layout col=lane&15, row=(lane>>4)*4+reg
    const int cc = lane & 15, rr = (lane >> 4) << 2;
#pragma unroll
    for (int q = 0; q < 2; q++)
#pragma unroll
        for (int r2 = 0; r2 < 2; r2++)
#pragma unroll
            for (int m = 0; m < 4; m++)
#pragma unroll
                for (int n = 0; n < 2; n++) {
                    const int colG = bn * 256 + r2 * 128 + wn * 32 + n * 16 + cc;
                    const int rowG = bm * 256 + q * 128 + wm * 64 + m * 16 + rr;
                    const float bv = bias[colG];
#pragma unroll
                    for (int reg = 0; reg < 4; reg++) {
                        float v = acc[q][r2][m][n][reg] + bv;
                        v = fmaxf(v, 0.0f);
                        Cg[(size_t)(rowG + reg) * N + colG] = (__bf16)v;
                    }
                }
#undef STAGE
#undef LDF
#undef LOAD_A
#undef LOAD_B
#undef MFMA_Q
#undef VMW
}

// ---------------- head: out[b,j] = h2[b,:] . Wq3[:,j] + bq3[j], j<3, K=512 ----------------
__global__ __launch_bounds__(256) void head_kernel(const __bf16* __restrict__ h2,
                                                   const float* __restrict__ Wq3,
                                                   const float* __restrict__ bq3,
                                                   float* __restrict__ out) {
    const int wave = threadIdx.x >> 6, lane = threadIdx.x & 63;
    const int row = blockIdx.x * 4 + wave;
    const bf16x8 hv = *(const bf16x8*)(h2 + (size_t)row * 512 + lane * 8);
    float s0 = 0.f, s1 = 0.f, s2 = 0.f;
#pragma unroll
    for (int i = 0; i < 8; i++) {
        const float hf = (float)hv[i];
        const int k = lane * 8 + i;
        s0 += hf * Wq3[k * 3 + 0];
        s1 += hf * Wq3[k * 3 + 1];
        s2 += hf * Wq3[k * 3 + 2];
    }
#pragma unroll
    for (int off = 32; off > 0; off >>= 1) {
        s0 += __shfl_xor(s0, off);
        s1 += __shfl_xor(s1, off);
        s2 += __shfl_xor(s2, off);
    }
    if (lane == 0) {
        float* o = out + (size_t)row * 3;
        o[0] = s0 + bq3[0];
        o[1] = s1 + bq3[1];
        o[2] = s2 + bq3[2];
    }
}

extern "C" void kernel_launch(void* const* d_in, const int* in_sizes, int n_in,
                              void* d_out, int out_size, void* d_ws, size_t ws_size,
                              hipStream_t stream) {
    const float* obs = (const float*)d_in[0];
    const float* act = (const float*)d_in[1];
    const float* Wp1 = (const float*)d_in[2];  const float* bp1 = (const float*)d_in[3];
    const float* Wp2 = (const float*)d_in[4];  const float* bp2 = (const float*)d_in[5];
    const float* Wt1 = (const float*)d_in[6];  const float* bt1 = (const float*)d_in[7];
    const float* Wt2 = (const float*)d_in[8];  const float* bt2 = (const float*)d_in[9];
    const float* Wr1 = (const float*)d_in[10]; const float* br1 = (const float*)d_in[11];
    const float* Wr2 = (const float*)d_in[12]; const float* br2 = (const float*)d_in[13];
    const float* Wq1 = (const float*)d_in[14]; const float* bq1 = (const float*)d_in[15];
    const float* Wq2 = (const float*)d_in[16]; const float* bq2 = (const float*)d_in[17];
    const float* Wq3 = (const float*)d_in[18]; const float* bq3 = (const float*)d_in[19];
    float* out = (float*)d_out;

    char* ws = (char*)d_ws;
    __bf16* enc = (__bf16*)(ws);                            // 16384*2688*2 = 88,080,384
    __bf16* h1  = (__bf16*)(ws + 88080384);                 // 16384*1024*2 = 33,554,432
    __bf16* h2  = (__bf16*)(ws + 88080384 + 33554432);      // 16384*512*2  = 16,777,216
    __bf16* w1t = (__bf16*)(ws + 138412032);                // 1024*2688*2  = 5,505,024
    __bf16* w2t = (__bf16*)(ws + 143917056);                // 512*1024*2   = 1,048,576

    // weight transposes (f32 -> bf16, [K,N] -> [N,K])
    transpose_bf16_k<<<dim3(2688 / 64, 1024 / 64), 256, 0, stream>>>(Wq1, w1t, 2688, 1024);
    transpose_bf16_k<<<dim3(1024 / 64, 512 / 64), 256, 0, stream>>>(Wq2, w2t, 1024, 512);

    // encoders: 49152 rows, 256 rows/block
    enc_kernel<5, 0><<<dim3(192, 9), 256, 0, stream>>>(obs, act, Wp1, bp1, Wp2, bp2, enc, 0, 0);
    enc_kernel<12, 1><<<dim3(192, 2), 256, 0, stream>>>(obs, act, Wt1, bt1, Wt2, bt2, enc, 9, 18);
    enc_kernel<9, 2><<<dim3(192, 3), 256, 0, stream>>>(obs, act, Wr1, br1, Wr2, br2, enc, 11, 117);

    // q head: 256x256 MFMA GEMMs
    gemm256_relu<<<dim3(64 * 4), 512, 0, stream>>>(enc, w1t, bq1, h1, 1024, 2688, 2);
    gemm256_relu<<<dim3(64 * 2), 512, 0, stream>>>(h1, w2t, bq2, h2, 512, 1024, 1);
    head_kernel<<<16384 / 4, 256, 0, stream>>>(h2, Wq3, bq3, out);
}

// Round 5
// 231.858 us; speedup vs baseline: 1.0711x; 1.0711x over previous
//
#include <hip/hip_runtime.h>
#include <hip/hip_bf16.h>
#include <cstdint>

typedef __bf16 bf16x8 __attribute__((ext_vector_type(8)));
typedef float f32x4 __attribute__((ext_vector_type(4)));

// ---------------- async global->LDS (16B per lane) ----------------
__device__ __forceinline__ void gld16(const __bf16* g, __bf16* lds) {
    __builtin_amdgcn_global_load_lds(
        (__attribute__((address_space(1))) void*)(uintptr_t)g,
        (__attribute__((address_space(3))) void*)(uint32_t)(uintptr_t)lds,
        16, 0, 0);
}

// ---------------- transpose + f32->bf16 convert: out[C][R] = in[R][C] ----------------
__global__ __launch_bounds__(256) void transpose_bf16_k(const float* __restrict__ in,
                                                        __bf16* __restrict__ out,
                                                        int R, int C) {
    __shared__ float t[64][65];
    const int r0 = blockIdx.x * 64, c0 = blockIdx.y * 64;
    const int tid = threadIdx.x;
#pragma unroll
    for (int i = 0; i < 16; i++) {
        int idx = i * 256 + tid;
        int rr = idx >> 6, cc = idx & 63;
        t[rr][cc] = in[(size_t)(r0 + rr) * C + (c0 + cc)];
    }
    __syncthreads();
#pragma unroll
    for (int i = 0; i < 16; i++) {
        int idx = i * 256 + tid;
        int rr = idx >> 6, cc = idx & 63;
        out[(size_t)(c0 + rr) * R + (r0 + cc)] = (__bf16)t[cc][rr];
    }
}

// ---------------- encoder: per (row, segment) 2-layer MLP ----------------
template <int DIN, int MODE>
__global__ __launch_bounds__(256) void enc_kernel(const float* __restrict__ obs,
                                                  const float* __restrict__ act,
                                                  const float* __restrict__ W1g,
                                                  const float* __restrict__ b1g,
                                                  const float* __restrict__ W2g,
                                                  const float* __restrict__ b2g,
                                                  __bf16* __restrict__ enc,
                                                  int kgBase, int xBase) {
    const int k = blockIdx.y;
    const int kg = kgBase + k;
    __shared__ float sW1[DIN * 32];
    __shared__ float sW2[32 * 64];
    __shared__ float sb1[32];
    __shared__ float sb2[64];
    const int tid = threadIdx.x;
    for (int i = tid; i < DIN * 32; i += 256) sW1[i] = W1g[k * DIN * 32 + i];
    for (int i = tid; i < 2048; i += 256) sW2[i] = W2g[k * 2048 + i];
    if (tid < 32) sb1[tid] = b1g[k * 32 + tid];
    else if (tid < 96) sb2[tid - 32] = b2g[k * 64 + (tid - 32)];
    __syncthreads();

    const int r = blockIdx.x * 256 + tid;
    const float* orow = obs + (size_t)r * 144;
    float x[DIN];
    if (MODE == 0) {
        x[0] = orow[2 * k];
        x[1] = orow[2 * k + 1];
        const float* arow = act + (size_t)r * 3;
        x[2] = arow[0]; x[3] = arow[1]; x[4] = arow[2];
    } else {
#pragma unroll
        for (int i = 0; i < DIN; i++) x[i] = orow[xBase + DIN * k + i];
    }

    float h[32];
#pragma unroll
    for (int o = 0; o < 32; o++) {
        float a = sb1[o];
#pragma unroll
        for (int i = 0; i < DIN; i++) a += x[i] * sW1[i * 32 + o];
        h[o] = fmaxf(a, 0.01f * a);
    }

    __bf16* dst = enc + (size_t)r * 896 + kg * 64;
#pragma unroll
    for (int og = 0; og < 8; og++) {
        bf16x8 tmp;
#pragma unroll
        for (int oi = 0; oi < 8; oi++) {
            const int o = og * 8 + oi;
            float a = sb2[o];
#pragma unroll
            for (int hh = 0; hh < 32; hh++) a += h[hh] * sW2[hh * 64 + o];
            a = fmaxf(a, 0.01f * a);
            tmp[oi] = (__bf16)a;
        }
        *(bf16x8*)&dst[og * 8] = tmp;
    }
}

// ---------------- 256xBN 4-phase bf16 GEMM with register read-ahead ----------------
// NB = n-tiles (16 cols) per wave. BN = NB*128. 8 waves (2M x 4N), BK=64.
// Double-buffered LDS (XOR-swizzled both-sides), 1-tile-ahead global_load_lds,
// ds_reads issued one phase ahead, counted lgkmcnt, single deep-distance vmcnt(0)/tile.
// Quadrant order (0,0)->(0,1)->(1,0)->(1,1): last phase uses only {a1,b1} so the
// W4 read-ahead may safely overwrite {a0,b0} (register-lifetime fix of round 4).
template <int NB>
__global__ __launch_bounds__(512, 2) void gemm256_relu(const __bf16* __restrict__ Ag,
                                                       const __bf16* __restrict__ Btg,
                                                       const float* __restrict__ bias,
                                                       __bf16* __restrict__ Cg,
                                                       int N, int K, int lgn) {
    __shared__ __align__(16) __bf16 ldsA[2][2][128 * 64];
    __shared__ __align__(16) __bf16 ldsB[2][2][NB * 64 * 64];
    const int tid = threadIdx.x;
    const int wid = tid >> 6, lane = tid & 63;
    const int wm = wid >> 2, wn = wid & 3;
    const int fr = lane & 15, kq = lane >> 4;

    // XCD-aware swizzle; bn fastest within each XCD chunk (A-panel shared in XCD L2)
    const int chunk = gridDim.x >> 3;
    const int wg = (blockIdx.x & 7) * chunk + (blockIdx.x >> 3);
    const int bn = wg & ((1 << lgn) - 1), bm = wg >> lgn;

    // staging source (pre-swizzled): chunk c -> row=c>>3, slot=(c&7)^(row&7)
    const int c0 = tid, c1 = tid + 512;
    const int r0 = c0 >> 3, s0 = (c0 & 7) ^ (r0 & 7);
    const int r1 = c1 >> 3, s1 = (c1 & 7) ^ (r1 & 7);
    const size_t aH = (size_t)128 * K;          // A half stride (rows)
    const size_t bH = (size_t)(NB * 64) * K;    // B half stride
    const __bf16* aB0 = Ag + (size_t)(bm * 256 + r0) * K + s0 * 8;
    const __bf16* aB1 = Ag + (size_t)(bm * 256 + r1) * K + s1 * 8;
    const __bf16* bB0 = Btg + (size_t)(bn * (NB * 128) + r0) * K + s0 * 8;
    const __bf16* bB1 = Btg + (size_t)(bn * (NB * 128) + r1) * K + s1 * 8;

    f32x4 acc[2][2][4][NB] = {};
    bf16x8 a0[4][2], a1[4][2], b0[NB][2], b1[NB][2];

#define STAGE_A(BUF, H, KO)                                   \
    do {                                                      \
        __bf16* d_ = &ldsA[BUF][H][0];                        \
        gld16(aB0 + (H)*aH + (KO), d_ + c0 * 8);              \
        gld16(aB1 + (H)*aH + (KO), d_ + c1 * 8);              \
    } while (0)
#define STAGE_B(BUF, H, KO)                                   \
    do {                                                      \
        __bf16* d_ = &ldsB[BUF][H][0];                        \
        gld16(bB0 + (H)*bH + (KO), d_ + c0 * 8);              \
        if constexpr (NB == 2) gld16(bB1 + (H)*bH + (KO), d_ + c1 * 8); \
    } while (0)

#define LDFA(BUF, H, ROW, KS) \
    (*(const bf16x8*)&ldsA[BUF][H][(ROW) * 64 + ((((KS)*4 + kq) ^ ((ROW)&7)) * 8)])
#define LDFB(BUF, H, ROW, KS) \
    (*(const bf16x8*)&ldsB[BUF][H][(ROW) * 64 + ((((KS)*4 + kq) ^ ((ROW)&7)) * 8)])

#define LOAD_A(BUF, H, DST)                                   \
    _Pragma("unroll") for (int m = 0; m < 4; m++)             \
        _Pragma("unroll") for (int ks = 0; ks < 2; ks++)      \
            DST[m][ks] = LDFA(BUF, H, wm * 64 + m * 16 + fr, ks);
#define LOAD_B(BUF, H, DST)                                   \
    _Pragma("unroll") for (int n = 0; n < NB; n++)            \
        _Pragma("unroll") for (int ks = 0; ks < 2; ks++)      \
            DST[n][ks] = LDFB(BUF, H, wn * (NB * 16) + n * 16 + fr, ks);

#define MM(Q, R, AR, BR)                                      \
    __builtin_amdgcn_s_setprio(1);                            \
    _Pragma("unroll") for (int ks = 0; ks < 2; ks++)          \
        _Pragma("unroll") for (int m = 0; m < 4; m++)         \
            _Pragma("unroll") for (int n = 0; n < NB; n++)    \
                acc[Q][R][m][n] = __builtin_amdgcn_mfma_f32_16x16x32_bf16( \
                    AR[m][ks], BR[n][ks], acc[Q][R][m][n], 0, 0, 0); \
    __builtin_amdgcn_s_setprio(0);

#define SB0 __builtin_amdgcn_sched_barrier(0)
#define BAR __builtin_amdgcn_s_barrier()
#define LGKM_B1                                               \
    if constexpr (NB == 2) asm volatile("s_waitcnt lgkmcnt(4)" ::: "memory"); \
    else asm volatile("s_waitcnt lgkmcnt(2)" ::: "memory");
#define LGKM(NSTR) asm volatile("s_waitcnt lgkmcnt(" NSTR ")" ::: "memory")
#define VMW0 asm volatile("s_waitcnt vmcnt(0)" ::: "memory")

    const int NT = K >> 6;

    // prologue: stage tile 0, drain, issue phase-1 reads
    STAGE_A(0, 0, 0);
    STAGE_B(0, 0, 0);
    STAGE_B(0, 1, 0);
    STAGE_A(0, 1, 0);
    VMW0;
    BAR;
    LOAD_A(0, 0, a0)
    LOAD_B(0, 0, b0)
    SB0;

    for (int t = 0; t < NT; ++t) {
        const int buf = t & 1, nb = buf ^ 1;
        const int kO = (t + 1) << 6;
        const bool st = (t + 1 < NT);

        // W1: Q(0,0); read-ahead b1; stage all of next tile -> other buffer
        LOAD_B(buf, 1, b1)
        if (st) {
            STAGE_A(nb, 0, kO);
            STAGE_B(nb, 0, kO);
            STAGE_B(nb, 1, kO);
            STAGE_A(nb, 1, kO);
        }
        SB0;
        BAR;
        LGKM_B1;      // a0,b0 landed; b1 in flight
        SB0;
        MM(0, 0, a0, b0)

        // W2: Q(0,1); read-ahead a1
        LOAD_A(buf, 1, a1)
        SB0;
        BAR;
        LGKM("8");    // b1 landed; a1 in flight
        SB0;
        MM(0, 1, a0, b1)

        // W3: Q(1,0) — b0 consumed here, before the read-ahead overwrites it
        BAR;
        LGKM("0");    // a1 landed
        SB0;
        MM(1, 0, a1, b0)

        // tile boundary: staged loads (issued W1, ~3 phases ago) landed
        VMW0;
        BAR;
        // W4: Q(1,1); read-ahead next tile's a0,b0 ({a0,b0} are dead now)
        if (st) {
            LOAD_A(nb, 0, a0)
            LOAD_B(nb, 0, b0)
        }
        SB0;
        MM(1, 1, a1, b1)
    }

    // epilogue: C/D layout col=lane&15, row=(lane>>4)*4+reg
    const int cc = lane & 15, rr = (lane >> 4) << 2;
#pragma unroll
    for (int q = 0; q < 2; q++)
#pragma unroll
        for (int r2 = 0; r2 < 2; r2++)
#pragma unroll
            for (int m = 0; m < 4; m++)
#pragma unroll
                for (int n = 0; n < NB; n++) {
                    const int colG = bn * (NB * 128) + r2 * (NB * 64) + wn * (NB * 16) + n * 16 + cc;
                    const int rowG = bm * 256 + q * 128 + wm * 64 + m * 16 + rr;
                    const float bv = bias[colG];
#pragma unroll
                    for (int reg = 0; reg < 4; reg++) {
                        float v = acc[q][r2][m][n][reg] + bv;
                        v = fmaxf(v, 0.0f);
                        Cg[(size_t)(rowG + reg) * N + colG] = (__bf16)v;
                    }
                }
#undef STAGE_A
#undef STAGE_B
#undef LDFA
#undef LDFB
#undef LOAD_A
#undef LOAD_B
#undef MM
#undef SB0
#undef BAR
#undef LGKM_B1
#undef LGKM
#undef VMW0
}

// ---------------- head: out[b,j] = h2[b,:] . Wq3[:,j] + bq3[j], j<3, K=512 ----------------
__global__ __launch_bounds__(256) void head_kernel(const __bf16* __restrict__ h2,
                                                   const float* __restrict__ Wq3,
                                                   const float* __restrict__ bq3,
                                                   float* __restrict__ out) {
    const int wave = threadIdx.x >> 6, lane = threadIdx.x & 63;
    const int row = blockIdx.x * 4 + wave;
    const bf16x8 hv = *(const bf16x8*)(h2 + (size_t)row * 512 + lane * 8);
    float s0 = 0.f, s1 = 0.f, s2 = 0.f;
#pragma unroll
    for (int i = 0; i < 8; i++) {
        const float hf = (float)hv[i];
        const int k = lane * 8 + i;
        s0 += hf * Wq3[k * 3 + 0];
        s1 += hf * Wq3[k * 3 + 1];
        s2 += hf * Wq3[k * 3 + 2];
    }
#pragma unroll
    for (int off = 32; off > 0; off >>= 1) {
        s0 += __shfl_xor(s0, off);
        s1 += __shfl_xor(s1, off);
        s2 += __shfl_xor(s2, off);
    }
    if (lane == 0) {
        float* o = out + (size_t)row * 3;
        o[0] = s0 + bq3[0];
        o[1] = s1 + bq3[1];
        o[2] = s2 + bq3[2];
    }
}

extern "C" void kernel_launch(void* const* d_in, const int* in_sizes, int n_in,
                              void* d_out, int out_size, void* d_ws, size_t ws_size,
                              hipStream_t stream) {
    const float* obs = (const float*)d_in[0];
    const float* act = (const float*)d_in[1];
    const float* Wp1 = (const float*)d_in[2];  const float* bp1 = (const float*)d_in[3];
    const float* Wp2 = (const float*)d_in[4];  const float* bp2 = (const float*)d_in[5];
    const float* Wt1 = (const float*)d_in[6];  const float* bt1 = (const float*)d_in[7];
    const float* Wt2 = (const float*)d_in[8];  const float* bt2 = (const float*)d_in[9];
    const float* Wr1 = (const float*)d_in[10]; const float* br1 = (const float*)d_in[11];
    const float* Wr2 = (const float*)d_in[12]; const float* br2 = (const float*)d_in[13];
    const float* Wq1 = (const float*)d_in[14]; const float* bq1 = (const float*)d_in[15];
    const float* Wq2 = (const float*)d_in[16]; const float* bq2 = (const float*)d_in[17];
    const float* Wq3 = (const float*)d_in[18]; const float* bq3 = (const float*)d_in[19];
    float* out = (float*)d_out;

    char* ws = (char*)d_ws;
    __bf16* enc = (__bf16*)(ws);                            // 16384*2688*2 = 88,080,384
    __bf16* h1  = (__bf16*)(ws + 88080384);                 // 16384*1024*2 = 33,554,432
    __bf16* h2  = (__bf16*)(ws + 88080384 + 33554432);      // 16384*512*2  = 16,777,216
    __bf16* w1t = (__bf16*)(ws + 138412032);                // 1024*2688*2  = 5,505,024
    __bf16* w2t = (__bf16*)(ws + 143917056);                // 512*1024*2   = 1,048,576

    // weight transposes (f32 -> bf16, [K,N] -> [N,K])
    transpose_bf16_k<<<dim3(2688 / 64, 1024 / 64), 256, 0, stream>>>(Wq1, w1t, 2688, 1024);
    transpose_bf16_k<<<dim3(1024 / 64, 512 / 64), 256, 0, stream>>>(Wq2, w2t, 1024, 512);

    // encoders: 49152 rows, 256 rows/block
    enc_kernel<5, 0><<<dim3(192, 9), 256, 0, stream>>>(obs, act, Wp1, bp1, Wp2, bp2, enc, 0, 0);
    enc_kernel<12, 1><<<dim3(192, 2), 256, 0, stream>>>(obs, act, Wt1, bt1, Wt2, bt2, enc, 9, 18);
    enc_kernel<9, 2><<<dim3(192, 3), 256, 0, stream>>>(obs, act, Wr1, br1, Wr2, br2, enc, 11, 117);

    // q head: NB=2 -> 256x256 tile; NB=1 -> 256x128 tile (both 256 blocks = 1/CU)
    gemm256_relu<2><<<dim3(256), 512, 0, stream>>>(enc, w1t, bq1, h1, 1024, 2688, 2);
    gemm256_relu<1><<<dim3(256), 512, 0, stream>>>(h1, w2t, bq2, h2, 512, 1024, 2);
    head_kernel<<<16384 / 4, 256, 0, stream>>>(h2, Wq3, bq3, out);
}

// Round 6
// 167.489 us; speedup vs baseline: 1.4827x; 1.3843x over previous
//
#include <hip/hip_runtime.h>
#include <hip/hip_bf16.h>
#include <cstdint>

typedef __bf16 bf16x8 __attribute__((ext_vector_type(8)));
typedef float f32x4 __attribute__((ext_vector_type(4)));

// ---------------- async global->LDS (16B per lane) ----------------
__device__ __forceinline__ void gld16(const __bf16* g, __bf16* lds) {
    __builtin_amdgcn_global_load_lds(
        (__attribute__((address_space(1))) void*)(uintptr_t)g,
        (__attribute__((address_space(3))) void*)(uint32_t)(uintptr_t)lds,
        16, 0, 0);
}

// ---------------- transpose + f32->bf16 convert: out[C][R] = in[R][C] ----------------
__global__ __launch_bounds__(256) void transpose_bf16_k(const float* __restrict__ in,
                                                        __bf16* __restrict__ out,
                                                        int R, int C) {
    __shared__ float t[64][65];
    const int r0 = blockIdx.x * 64, c0 = blockIdx.y * 64;
    const int tid = threadIdx.x;
#pragma unroll
    for (int i = 0; i < 16; i++) {
        int idx = i * 256 + tid;
        int rr = idx >> 6, cc = idx & 63;
        t[rr][cc] = in[(size_t)(r0 + rr) * C + (c0 + cc)];
    }
    __syncthreads();
#pragma unroll
    for (int i = 0; i < 16; i++) {
        int idx = i * 256 + tid;
        int rr = idx >> 6, cc = idx & 63;
        out[(size_t)(c0 + rr) * R + (r0 + cc)] = (__bf16)t[cc][rr];
    }
}

// ---------------- weight packing for fused encoder ----------------
// w1p: [3072 W1-flat][448 b1][896 b2] f32; w2t: [14][64 out][32 k] bf16
__global__ __launch_bounds__(256) void pack_weights(const float* __restrict__ Wp1, const float* __restrict__ bp1,
                                                    const float* __restrict__ Wp2, const float* __restrict__ bp2,
                                                    const float* __restrict__ Wt1, const float* __restrict__ bt1,
                                                    const float* __restrict__ Wt2, const float* __restrict__ bt2,
                                                    const float* __restrict__ Wr1, const float* __restrict__ br1,
                                                    const float* __restrict__ Wr2, const float* __restrict__ br2,
                                                    float* __restrict__ w1p, __bf16* __restrict__ w2t) {
    const int s = blockIdx.x, tid = threadIdx.x;
    int ks, din, w1off;
    const float *W1, *B1, *W2, *B2;
    if (s < 9)      { ks = s;      din = 5;  w1off = s * 160;
                      W1 = Wp1; B1 = bp1; W2 = Wp2; B2 = bp2; }
    else if (s < 11){ ks = s - 9;  din = 12; w1off = 1440 + ks * 384;
                      W1 = Wt1; B1 = bt1; W2 = Wt2; B2 = bt2; }
    else            { ks = s - 11; din = 9;  w1off = 2208 + ks * 288;
                      W1 = Wr1; B1 = br1; W2 = Wr2; B2 = br2; }
    W1 += ks * din * 32; B1 += ks * 32; W2 += ks * 2048; B2 += ks * 64;
    for (int i = tid; i < din * 32; i += 256) w1p[w1off + i] = W1[i];
    if (tid < 32) w1p[3072 + s * 32 + tid] = B1[tid];
    if (tid < 64) w1p[3520 + s * 64 + tid] = B2[tid];
    for (int i = tid; i < 2048; i += 256) {
        const int o = i >> 5, k = i & 31;
        w2t[s * 2048 + i] = (__bf16)W2[k * 64 + o];
    }
}

// ---------------- fused encoder: all 14 segments, layer1 VALU + layer2 MFMA ----------------
// 192 threads (3 waves), 192 rows/block, 256 blocks. h staged in LDS (bf16, row
// stride 40 elems = 80B -> even bank spread), W2^T B-frags read from global (L2-hot).
__global__ __launch_bounds__(192) void enc_fused(const float* __restrict__ obs,
                                                 const float* __restrict__ act,
                                                 const float* __restrict__ w1p,
                                                 const __bf16* __restrict__ w2t,
                                                 __bf16* __restrict__ enc) {
    __shared__ float sW[4416];             // [3072 W1][448 b1][896 b2]
    __shared__ __bf16 sH[2][192 * 40];     // dbuf h tiles
    const int tid = threadIdx.x;
    for (int i = tid; i < 4416; i += 192) sW[i] = w1p[i];
    const int row = blockIdx.x * 192 + tid;
    const float* orow = obs + (size_t)row * 144;
    const float a0 = act[row * 3], a1 = act[row * 3 + 1], a2 = act[row * 3 + 2];
    const int wv = tid >> 6, lane = tid & 63;
    const int fr = lane & 15, kq = lane >> 4;
    const int rq = (lane >> 4) << 2;
    __syncthreads();
    int buf = 0;

    auto l2 = [&](int s) {
        __syncthreads();
        bf16x8 bfr[4], afr[4];
#pragma unroll
        for (int n = 0; n < 4; n++)
            bfr[n] = *(const bf16x8*)&w2t[(s * 64 + n * 16 + fr) * 32 + kq * 8];
#pragma unroll
        for (int m = 0; m < 4; m++)
            afr[m] = *(const bf16x8*)&sH[buf][(wv * 64 + m * 16 + fr) * 40 + kq * 8];
        f32x4 acc[4][4] = {};
#pragma unroll
        for (int m = 0; m < 4; m++)
#pragma unroll
            for (int n = 0; n < 4; n++)
                acc[m][n] = __builtin_amdgcn_mfma_f32_16x16x32_bf16(afr[m], bfr[n], acc[m][n], 0, 0, 0);
        const float* b2 = sW + 3520 + s * 64;
#pragma unroll
        for (int m = 0; m < 4; m++) {
            const size_t rG = (size_t)blockIdx.x * 192 + wv * 64 + m * 16 + rq;
#pragma unroll
            for (int n = 0; n < 4; n++) {
                const float bv = b2[n * 16 + fr];
#pragma unroll
                for (int rg = 0; rg < 4; rg++) {
                    float v = acc[m][n][rg] + bv;
                    v = fmaxf(v, 0.01f * v);
                    enc[(rG + rg) * 896 + s * 64 + n * 16 + fr] = (__bf16)v;
                }
            }
        }
        buf ^= 1;
    };

#define L1(DIN, W1OFF, SGI, XLOAD)                                   \
    {                                                                \
        float x[DIN];                                                \
        XLOAD;                                                       \
        const float* w1 = sW + (W1OFF);                              \
        const float* b1 = sW + 3072 + (SGI) * 32;                    \
        float h[32];                                                 \
        _Pragma("unroll") for (int o = 0; o < 32; o++) {             \
            float a_ = b1[o];                                        \
            _Pragma("unroll") for (int i = 0; i < DIN; i++)          \
                a_ += x[i] * w1[i * 32 + o];                         \
            h[o] = fmaxf(a_, 0.01f * a_);                            \
        }                                                            \
        __bf16* hr = &sH[buf][tid * 40];                             \
        _Pragma("unroll") for (int sl = 0; sl < 4; sl++) {           \
            bf16x8 t_;                                               \
            _Pragma("unroll") for (int j = 0; j < 8; j++)            \
                t_[j] = (__bf16)h[sl * 8 + j];                       \
            *(bf16x8*)&hr[sl * 8] = t_;                              \
        }                                                            \
    }

    for (int k = 0; k < 9; k++) {
        L1(5, k * 160, k,
           { x[0] = orow[2 * k]; x[1] = orow[2 * k + 1]; x[2] = a0; x[3] = a1; x[4] = a2; })
        l2(k);
    }
    for (int k = 0; k < 2; k++) {
        L1(12, 1440 + k * 384, 9 + k,
           { _Pragma("unroll") for (int i = 0; i < 12; i++) x[i] = orow[18 + 12 * k + i]; })
        l2(9 + k);
    }
    for (int k = 0; k < 3; k++) {
        L1(9, 2208 + k * 288, 11 + k,
           { _Pragma("unroll") for (int i = 0; i < 9; i++) x[i] = orow[117 + 9 * k + i]; })
        l2(11 + k);
    }
#undef L1
}

// ---------------- 256xBN 4-phase bf16 GEMM with register read-ahead ----------------
// (unchanged from round 5 — validated)
template <int NB>
__global__ __launch_bounds__(512, 2) void gemm256_relu(const __bf16* __restrict__ Ag,
                                                       const __bf16* __restrict__ Btg,
                                                       const float* __restrict__ bias,
                                                       __bf16* __restrict__ Cg,
                                                       int N, int K, int lgn) {
    __shared__ __align__(16) __bf16 ldsA[2][2][128 * 64];
    __shared__ __align__(16) __bf16 ldsB[2][2][NB * 64 * 64];
    const int tid = threadIdx.x;
    const int wid = tid >> 6, lane = tid & 63;
    const int wm = wid >> 2, wn = wid & 3;
    const int fr = lane & 15, kq = lane >> 4;

    const int chunk = gridDim.x >> 3;
    const int wg = (blockIdx.x & 7) * chunk + (blockIdx.x >> 3);
    const int bn = wg & ((1 << lgn) - 1), bm = wg >> lgn;

    const int c0 = tid, c1 = tid + 512;
    const int r0 = c0 >> 3, s0 = (c0 & 7) ^ (r0 & 7);
    const int r1 = c1 >> 3, s1 = (c1 & 7) ^ (r1 & 7);
    const size_t aH = (size_t)128 * K;
    const size_t bH = (size_t)(NB * 64) * K;
    const __bf16* aB0 = Ag + (size_t)(bm * 256 + r0) * K + s0 * 8;
    const __bf16* aB1 = Ag + (size_t)(bm * 256 + r1) * K + s1 * 8;
    const __bf16* bB0 = Btg + (size_t)(bn * (NB * 128) + r0) * K + s0 * 8;
    const __bf16* bB1 = Btg + (size_t)(bn * (NB * 128) + r1) * K + s1 * 8;

    f32x4 acc[2][2][4][NB] = {};
    bf16x8 a0[4][2], a1[4][2], b0[NB][2], b1[NB][2];

#define STAGE_A(BUF, H, KO)                                   \
    do {                                                      \
        __bf16* d_ = &ldsA[BUF][H][0];                        \
        gld16(aB0 + (H)*aH + (KO), d_ + c0 * 8);              \
        gld16(aB1 + (H)*aH + (KO), d_ + c1 * 8);              \
    } while (0)
#define STAGE_B(BUF, H, KO)                                   \
    do {                                                      \
        __bf16* d_ = &ldsB[BUF][H][0];                        \
        gld16(bB0 + (H)*bH + (KO), d_ + c0 * 8);              \
        if constexpr (NB == 2) gld16(bB1 + (H)*bH + (KO), d_ + c1 * 8); \
    } while (0)

#define LDFA(BUF, H, ROW, KS) \
    (*(const bf16x8*)&ldsA[BUF][H][(ROW) * 64 + ((((KS)*4 + kq) ^ ((ROW)&7)) * 8)])
#define LDFB(BUF, H, ROW, KS) \
    (*(const bf16x8*)&ldsB[BUF][H][(ROW) * 64 + ((((KS)*4 + kq) ^ ((ROW)&7)) * 8)])

#define LOAD_A(BUF, H, DST)                                   \
    _Pragma("unroll") for (int m = 0; m < 4; m++)             \
        _Pragma("unroll") for (int ks = 0; ks < 2; ks++)      \
            DST[m][ks] = LDFA(BUF, H, wm * 64 + m * 16 + fr, ks);
#define LOAD_B(BUF, H, DST)                                   \
    _Pragma("unroll") for (int n = 0; n < NB; n++)            \
        _Pragma("unroll") for (int ks = 0; ks < 2; ks++)      \
            DST[n][ks] = LDFB(BUF, H, wn * (NB * 16) + n * 16 + fr, ks);

#define MM(Q, R, AR, BR)                                      \
    __builtin_amdgcn_s_setprio(1);                            \
    _Pragma("unroll") for (int ks = 0; ks < 2; ks++)          \
        _Pragma("unroll") for (int m = 0; m < 4; m++)         \
            _Pragma("unroll") for (int n = 0; n < NB; n++)    \
                acc[Q][R][m][n] = __builtin_amdgcn_mfma_f32_16x16x32_bf16( \
                    AR[m][ks], BR[n][ks], acc[Q][R][m][n], 0, 0, 0); \
    __builtin_amdgcn_s_setprio(0);

#define SB0 __builtin_amdgcn_sched_barrier(0)
#define BAR __builtin_amdgcn_s_barrier()
#define LGKM_B1                                               \
    if constexpr (NB == 2) asm volatile("s_waitcnt lgkmcnt(4)" ::: "memory"); \
    else asm volatile("s_waitcnt lgkmcnt(2)" ::: "memory");
#define LGKM(NSTR) asm volatile("s_waitcnt lgkmcnt(" NSTR ")" ::: "memory")
#define VMW0 asm volatile("s_waitcnt vmcnt(0)" ::: "memory")

    const int NT = K >> 6;

    STAGE_A(0, 0, 0);
    STAGE_B(0, 0, 0);
    STAGE_B(0, 1, 0);
    STAGE_A(0, 1, 0);
    VMW0;
    BAR;
    LOAD_A(0, 0, a0)
    LOAD_B(0, 0, b0)
    SB0;

    for (int t = 0; t < NT; ++t) {
        const int buf = t & 1, nb = buf ^ 1;
        const int kO = (t + 1) << 6;
        const bool st = (t + 1 < NT);

        LOAD_B(buf, 1, b1)
        if (st) {
            STAGE_A(nb, 0, kO);
            STAGE_B(nb, 0, kO);
            STAGE_B(nb, 1, kO);
            STAGE_A(nb, 1, kO);
        }
        SB0;
        BAR;
        LGKM_B1;
        SB0;
        MM(0, 0, a0, b0)

        LOAD_A(buf, 1, a1)
        SB0;
        BAR;
        LGKM("8");
        SB0;
        MM(0, 1, a0, b1)

        BAR;
        LGKM("0");
        SB0;
        MM(1, 0, a1, b0)

        VMW0;
        BAR;
        if (st) {
            LOAD_A(nb, 0, a0)
            LOAD_B(nb, 0, b0)
        }
        SB0;
        MM(1, 1, a1, b1)
    }

    const int cc = lane & 15, rr = (lane >> 4) << 2;
#pragma unroll
    for (int q = 0; q < 2; q++)
#pragma unroll
        for (int r2 = 0; r2 < 2; r2++)
#pragma unroll
            for (int m = 0; m < 4; m++)
#pragma unroll
                for (int n = 0; n < NB; n++) {
                    const int colG = bn * (NB * 128) + r2 * (NB * 64) + wn * (NB * 16) + n * 16 + cc;
                    const int rowG = bm * 256 + q * 128 + wm * 64 + m * 16 + rr;
                    const float bv = bias[colG];
#pragma unroll
                    for (int reg = 0; reg < 4; reg++) {
                        float v = acc[q][r2][m][n][reg] + bv;
                        v = fmaxf(v, 0.0f);
                        Cg[(size_t)(rowG + reg) * N + colG] = (__bf16)v;
                    }
                }
#undef STAGE_A
#undef STAGE_B
#undef LDFA
#undef LDFB
#undef LOAD_A
#undef LOAD_B
#undef MM
#undef SB0
#undef BAR
#undef LGKM_B1
#undef LGKM
#undef VMW0
}

// ---------------- head: out[b,j] = h2[b,:] . Wq3[:,j] + bq3[j], j<3, K=512 ----------------
__global__ __launch_bounds__(256) void head_kernel(const __bf16* __restrict__ h2,
                                                   const float* __restrict__ Wq3,
                                                   const float* __restrict__ bq3,
                                                   float* __restrict__ out) {
    const int wave = threadIdx.x >> 6, lane = threadIdx.x & 63;
    const int row = blockIdx.x * 4 + wave;
    const bf16x8 hv = *(const bf16x8*)(h2 + (size_t)row * 512 + lane * 8);
    float s0 = 0.f, s1 = 0.f, s2 = 0.f;
#pragma unroll
    for (int i = 0; i < 8; i++) {
        const float hf = (float)hv[i];
        const int k = lane * 8 + i;
        s0 += hf * Wq3[k * 3 + 0];
        s1 += hf * Wq3[k * 3 + 1];
        s2 += hf * Wq3[k * 3 + 2];
    }
#pragma unroll
    for (int off = 32; off > 0; off >>= 1) {
        s0 += __shfl_xor(s0, off);
        s1 += __shfl_xor(s1, off);
        s2 += __shfl_xor(s2, off);
    }
    if (lane == 0) {
        float* o = out + (size_t)row * 3;
        o[0] = s0 + bq3[0];
        o[1] = s1 + bq3[1];
        o[2] = s2 + bq3[2];
    }
}

extern "C" void kernel_launch(void* const* d_in, const int* in_sizes, int n_in,
                              void* d_out, int out_size, void* d_ws, size_t ws_size,
                              hipStream_t stream) {
    const float* obs = (const float*)d_in[0];
    const float* act = (const float*)d_in[1];
    const float* Wp1 = (const float*)d_in[2];  const float* bp1 = (const float*)d_in[3];
    const float* Wp2 = (const float*)d_in[4];  const float* bp2 = (const float*)d_in[5];
    const float* Wt1 = (const float*)d_in[6];  const float* bt1 = (const float*)d_in[7];
    const float* Wt2 = (const float*)d_in[8];  const float* bt2 = (const float*)d_in[9];
    const float* Wr1 = (const float*)d_in[10]; const float* br1 = (const float*)d_in[11];
    const float* Wr2 = (const float*)d_in[12]; const float* br2 = (const float*)d_in[13];
    const float* Wq1 = (const float*)d_in[14]; const float* bq1 = (const float*)d_in[15];
    const float* Wq2 = (const float*)d_in[16]; const float* bq2 = (const float*)d_in[17];
    const float* Wq3 = (const float*)d_in[18]; const float* bq3 = (const float*)d_in[19];
    float* out = (float*)d_out;

    char* ws = (char*)d_ws;
    __bf16* enc = (__bf16*)(ws);                            // 88,080,384
    __bf16* h1  = (__bf16*)(ws + 88080384);                 // 33,554,432
    __bf16* h2  = (__bf16*)(ws + 88080384 + 33554432);      // 16,777,216
    __bf16* w1t = (__bf16*)(ws + 138412032);                // 5,505,024
    __bf16* w2t = (__bf16*)(ws + 143917056);                // 1,048,576
    float*  w1p = (float*)(ws + 144965632);                 // 17,664
    __bf16* w2e = (__bf16*)(ws + 144983296);                // 57,344

    // weight prep
    pack_weights<<<14, 256, 0, stream>>>(Wp1, bp1, Wp2, bp2, Wt1, bt1, Wt2, bt2,
                                         Wr1, br1, Wr2, br2, w1p, w2e);
    transpose_bf16_k<<<dim3(2688 / 64, 1024 / 64), 256, 0, stream>>>(Wq1, w1t, 2688, 1024);
    transpose_bf16_k<<<dim3(1024 / 64, 512 / 64), 256, 0, stream>>>(Wq2, w2t, 1024, 512);

    // fused encoders: 49152 rows, 192 rows/block, 256 blocks
    enc_fused<<<256, 192, 0, stream>>>(obs, act, w1p, w2e, enc);

    // q head
    gemm256_relu<2><<<dim3(256), 512, 0, stream>>>(enc, w1t, bq1, h1, 1024, 2688, 2);
    gemm256_relu<1><<<dim3(256), 512, 0, stream>>>(h1, w2t, bq2, h2, 512, 1024, 2);
    head_kernel<<<16384 / 4, 256, 0, stream>>>(h2, Wq3, bq3, out);
}

// Round 8
// 162.020 us; speedup vs baseline: 1.5328x; 1.0338x over previous
//
#include <hip/hip_runtime.h>
#include <hip/hip_bf16.h>
#include <cstdint>

typedef __bf16 bf16x8 __attribute__((ext_vector_type(8)));
typedef float f32x4 __attribute__((ext_vector_type(4)));

// ---------------- async global->LDS (16B per lane) ----------------
__device__ __forceinline__ void gld16(const __bf16* g, __bf16* lds) {
    __builtin_amdgcn_global_load_lds(
        (__attribute__((address_space(1))) void*)(uintptr_t)g,
        (__attribute__((address_space(3))) void*)(uint32_t)(uintptr_t)lds,
        16, 0, 0);
}

// ---------------- transpose + f32->bf16 convert: out[C][R] = in[R][C] ----------------
__global__ __launch_bounds__(256) void transpose_bf16_k(const float* __restrict__ in,
                                                        __bf16* __restrict__ out,
                                                        int R, int C) {
    __shared__ float t[64][65];
    const int r0 = blockIdx.x * 64, c0 = blockIdx.y * 64;
    const int tid = threadIdx.x;
#pragma unroll
    for (int i = 0; i < 16; i++) {
        int idx = i * 256 + tid;
        int rr = idx >> 6, cc = idx & 63;
        t[rr][cc] = in[(size_t)(r0 + rr) * C + (c0 + cc)];
    }
    __syncthreads();
#pragma unroll
    for (int i = 0; i < 16; i++) {
        int idx = i * 256 + tid;
        int rr = idx >> 6, cc = idx & 63;
        out[(size_t)(c0 + rr) * R + (r0 + cc)] = (__bf16)t[cc][rr];
    }
}

// ---------------- weight packing for fused encoder ----------------
__global__ __launch_bounds__(256) void pack_weights(const float* __restrict__ Wp1, const float* __restrict__ bp1,
                                                    const float* __restrict__ Wp2, const float* __restrict__ bp2,
                                                    const float* __restrict__ Wt1, const float* __restrict__ bt1,
                                                    const float* __restrict__ Wt2, const float* __restrict__ bt2,
                                                    const float* __restrict__ Wr1, const float* __restrict__ br1,
                                                    const float* __restrict__ Wr2, const float* __restrict__ br2,
                                                    float* __restrict__ w1p, __bf16* __restrict__ w2t) {
    const int s = blockIdx.x, tid = threadIdx.x;
    int ks, din, w1off;
    const float *W1, *B1, *W2, *B2;
    if (s < 9)      { ks = s;      din = 5;  w1off = s * 160;
                      W1 = Wp1; B1 = bp1; W2 = Wp2; B2 = bp2; }
    else if (s < 11){ ks = s - 9;  din = 12; w1off = 1440 + ks * 384;
                      W1 = Wt1; B1 = bt1; W2 = Wt2; B2 = bt2; }
    else            { ks = s - 11; din = 9;  w1off = 2208 + ks * 288;
                      W1 = Wr1; B1 = br1; W2 = Wr2; B2 = br2; }
    W1 += ks * din * 32; B1 += ks * 32; W2 += ks * 2048; B2 += ks * 64;
    for (int i = tid; i < din * 32; i += 256) w1p[w1off + i] = W1[i];
    if (tid < 32) w1p[3072 + s * 32 + tid] = B1[tid];
    if (tid < 64) w1p[3520 + s * 64 + tid] = B2[tid];
    for (int i = tid; i < 2048; i += 256) {
        const int o = i >> 5, k = i & 31;
        w2t[s * 2048 + i] = (__bf16)W2[k * 64 + o];
    }
}

// ---------------- fused encoder: all 14 segments, layer1 VALU + layer2 MFMA ----------------
__global__ __launch_bounds__(192) void enc_fused(const float* __restrict__ obs,
                                                 const float* __restrict__ act,
                                                 const float* __restrict__ w1p,
                                                 const __bf16* __restrict__ w2t,
                                                 __bf16* __restrict__ enc) {
    __shared__ float sW[4416];             // [3072 W1][448 b1][896 b2]
    __shared__ __bf16 sH[2][192 * 40];     // dbuf h tiles
    const int tid = threadIdx.x;
    for (int i = tid; i < 4416; i += 192) sW[i] = w1p[i];
    const int row = blockIdx.x * 192 + tid;
    const float* orow = obs + (size_t)row * 144;
    const float a0 = act[row * 3], a1 = act[row * 3 + 1], a2 = act[row * 3 + 2];
    const int wv = tid >> 6, lane = tid & 63;
    const int fr = lane & 15, kq = lane >> 4;
    const int rq = (lane >> 4) << 2;
    __syncthreads();
    int buf = 0;

    auto l2 = [&](int s) {
        __syncthreads();
        bf16x8 bfr[4], afr[4];
#pragma unroll
        for (int n = 0; n < 4; n++)
            bfr[n] = *(const bf16x8*)&w2t[(s * 64 + n * 16 + fr) * 32 + kq * 8];
#pragma unroll
        for (int m = 0; m < 4; m++)
            afr[m] = *(const bf16x8*)&sH[buf][(wv * 64 + m * 16 + fr) * 40 + kq * 8];
        f32x4 acc[4][4] = {};
#pragma unroll
        for (int m = 0; m < 4; m++)
#pragma unroll
            for (int n = 0; n < 4; n++)
                acc[m][n] = __builtin_amdgcn_mfma_f32_16x16x32_bf16(afr[m], bfr[n], acc[m][n], 0, 0, 0);
        const float* b2 = sW + 3520 + s * 64;
#pragma unroll
        for (int m = 0; m < 4; m++) {
            const size_t rG = (size_t)blockIdx.x * 192 + wv * 64 + m * 16 + rq;
#pragma unroll
            for (int n = 0; n < 4; n++) {
                const float bv = b2[n * 16 + fr];
#pragma unroll
                for (int rg = 0; rg < 4; rg++) {
                    float v = acc[m][n][rg] + bv;
                    v = fmaxf(v, 0.01f * v);
                    enc[(rG + rg) * 896 + s * 64 + n * 16 + fr] = (__bf16)v;
                }
            }
        }
        buf ^= 1;
    };

#define L1(DIN, W1OFF, SGI, XLOAD)                                   \
    {                                                                \
        float x[DIN];                                                \
        XLOAD;                                                       \
        const float* w1 = sW + (W1OFF);                              \
        const float* b1 = sW + 3072 + (SGI) * 32;                    \
        float h[32];                                                 \
        _Pragma("unroll") for (int o = 0; o < 32; o++) {             \
            float a_ = b1[o];                                        \
            _Pragma("unroll") for (int i = 0; i < DIN; i++)          \
                a_ += x[i] * w1[i * 32 + o];                         \
            h[o] = fmaxf(a_, 0.01f * a_);                            \
        }                                                            \
        __bf16* hr = &sH[buf][tid * 40];                             \
        _Pragma("unroll") for (int sl = 0; sl < 4; sl++) {           \
            bf16x8 t_;                                               \
            _Pragma("unroll") for (int j = 0; j < 8; j++)            \
                t_[j] = (__bf16)h[sl * 8 + j];                       \
            *(bf16x8*)&hr[sl * 8] = t_;                              \
        }                                                            \
    }

    for (int k = 0; k < 9; k++) {
        L1(5, k * 160, k,
           { x[0] = orow[2 * k]; x[1] = orow[2 * k + 1]; x[2] = a0; x[3] = a1; x[4] = a2; })
        l2(k);
    }
    for (int k = 0; k < 2; k++) {
        L1(12, 1440 + k * 384, 9 + k,
           { _Pragma("unroll") for (int i = 0; i < 12; i++) x[i] = orow[18 + 12 * k + i]; })
        l2(9 + k);
    }
    for (int k = 0; k < 3; k++) {
        L1(9, 2208 + k * 288, 11 + k,
           { _Pragma("unroll") for (int i = 0; i < 9; i++) x[i] = orow[117 + 9 * k + i]; })
        l2(11 + k);
    }
#undef L1
}

// ---------------- 256xBN bf16 GEMM: counted-vmcnt pipeline, race-free coverage ----------------
// Cross-wave rule: every ds_read of a staged region follows a BARRIER that is preceded
// (in ALL waves) by a vmcnt wait covering that region's loads.
//   W1: stage A0',B0'; vmcnt(4|3)  -> covers A1(t)   [read at W2, after W1.BAR]
//   W2: stage B1',A1'; (no wait)
//   W4: vmcnt(2)                   -> covers A0',B0' [read at W4 after BAR] and B1'
//                                     [read at next W1, after W4.BAR]
// Min outstanding = 2 (never drains); issue->deadline = 2-3 phases.
template <int NB>
__global__ __launch_bounds__(512, 2) void gemm256_relu(const __bf16* __restrict__ Ag,
                                                       const __bf16* __restrict__ Btg,
                                                       const float* __restrict__ bias,
                                                       __bf16* __restrict__ Cg,
                                                       int N, int K, int lgn) {
    __shared__ __align__(16) __bf16 ldsA[2][2][128 * 64];
    __shared__ __align__(16) __bf16 ldsB[2][2][NB * 64 * 64];
    const int tid = threadIdx.x;
    const int wid = tid >> 6, lane = tid & 63;
    const int wm = wid >> 2, wn = wid & 3;
    const int fr = lane & 15, kq = lane >> 4;

    const int chunk = gridDim.x >> 3;
    const int wg = (blockIdx.x & 7) * chunk + (blockIdx.x >> 3);
    const int bn = wg & ((1 << lgn) - 1), bm = wg >> lgn;

    const int c0 = tid, c1 = tid + 512;
    const int r0 = c0 >> 3, s0 = (c0 & 7) ^ (r0 & 7);
    const int r1 = c1 >> 3, s1 = (c1 & 7) ^ (r1 & 7);
    const size_t aH = (size_t)128 * K;
    const size_t bH = (size_t)(NB * 64) * K;
    const __bf16* aB0 = Ag + (size_t)(bm * 256 + r0) * K + s0 * 8;
    const __bf16* aB1 = Ag + (size_t)(bm * 256 + r1) * K + s1 * 8;
    const __bf16* bB0 = Btg + (size_t)(bn * (NB * 128) + r0) * K + s0 * 8;
    const __bf16* bB1 = Btg + (size_t)(bn * (NB * 128) + r1) * K + s1 * 8;

    f32x4 acc[2][2][4][NB] = {};
    bf16x8 a0[4][2], a1[4][2], b0[NB][2], b1[NB][2];

#define STAGE_A(BUF, H, KO)                                   \
    do {                                                      \
        __bf16* d_ = &ldsA[BUF][H][0];                        \
        gld16(aB0 + (H)*aH + (KO), d_ + c0 * 8);              \
        gld16(aB1 + (H)*aH + (KO), d_ + c1 * 8);              \
    } while (0)
#define STAGE_B(BUF, H, KO)                                   \
    do {                                                      \
        __bf16* d_ = &ldsB[BUF][H][0];                        \
        gld16(bB0 + (H)*bH + (KO), d_ + c0 * 8);              \
        if constexpr (NB == 2) gld16(bB1 + (H)*bH + (KO), d_ + c1 * 8); \
    } while (0)

#define LDFA(BUF, H, ROW, KS) \
    (*(const bf16x8*)&ldsA[BUF][H][(ROW) * 64 + ((((KS)*4 + kq) ^ ((ROW)&7)) * 8)])
#define LDFB(BUF, H, ROW, KS) \
    (*(const bf16x8*)&ldsB[BUF][H][(ROW) * 64 + ((((KS)*4 + kq) ^ ((ROW)&7)) * 8)])

#define LOAD_A(BUF, H, DST)                                   \
    _Pragma("unroll") for (int m = 0; m < 4; m++)             \
        _Pragma("unroll") for (int ks = 0; ks < 2; ks++)      \
            DST[m][ks] = LDFA(BUF, H, wm * 64 + m * 16 + fr, ks);
#define LOAD_B(BUF, H, DST)                                   \
    _Pragma("unroll") for (int n = 0; n < NB; n++)            \
        _Pragma("unroll") for (int ks = 0; ks < 2; ks++)      \
            DST[n][ks] = LDFB(BUF, H, wn * (NB * 16) + n * 16 + fr, ks);

#define MM(Q, R, AR, BR)                                      \
    __builtin_amdgcn_s_setprio(1);                            \
    _Pragma("unroll") for (int ks = 0; ks < 2; ks++)          \
        _Pragma("unroll") for (int m = 0; m < 4; m++)         \
            _Pragma("unroll") for (int n = 0; n < NB; n++)    \
                acc[Q][R][m][n] = __builtin_amdgcn_mfma_f32_16x16x32_bf16( \
                    AR[m][ks], BR[n][ks], acc[Q][R][m][n], 0, 0, 0); \
    __builtin_amdgcn_s_setprio(0);

#define SB0 __builtin_amdgcn_sched_barrier(0)
#define BAR __builtin_amdgcn_s_barrier()
#define LGKM_B1                                               \
    if constexpr (NB == 2) asm volatile("s_waitcnt lgkmcnt(4)" ::: "memory"); \
    else asm volatile("s_waitcnt lgkmcnt(2)" ::: "memory");
#define LGKM(NSTR) asm volatile("s_waitcnt lgkmcnt(" NSTR ")" ::: "memory")
#define VMW(NSTR) asm volatile("s_waitcnt vmcnt(" NSTR ")" ::: "memory")
#define VMW2(N2, N1)                                          \
    if constexpr (NB == 2) VMW(#N2); else VMW(#N1);

    const int NT = K >> 6;

    // prologue: stage tile 0 (A0,B0,B1,A1); cover all but A1 (read at W2(0))
    STAGE_A(0, 0, 0);
    STAGE_B(0, 0, 0);
    STAGE_B(0, 1, 0);
    STAGE_A(0, 1, 0);
    VMW("2");
    BAR;
    LOAD_A(0, 0, a0)
    LOAD_B(0, 0, b0)
    SB0;

    for (int t = 0; t < NT - 1; ++t) {
        const int buf = t & 1, nb = buf ^ 1;
        const int kO = (t + 1) << 6;

        // W1: stage A0',B0'; vmcnt covers A1(t) (leaves A0',B0' in flight)
        STAGE_A(nb, 0, kO);
        STAGE_B(nb, 0, kO);
        VMW2(4, 3);
        LOAD_B(buf, 1, b1)        // B1(t): covered by W4(t-1) VMW("2") + BAR
        SB0;
        BAR;
        LGKM_B1;
        SB0;
        MM(0, 0, a0, b0)

        // W2: stage B1',A1'
        STAGE_B(nb, 1, kO);
        STAGE_A(nb, 1, kO);
        LOAD_A(buf, 1, a1)        // A1(t): covered by W1 VMW2(4,3) + BAR
        SB0;
        BAR;
        LGKM("8");
        SB0;
        MM(0, 1, a0, b1)

        // W3
        BAR;
        LGKM("0");
        SB0;
        MM(1, 0, a1, b0)

        // W4: cover A0',B0',B1' (leaves only A1' in flight)
        VMW("2");
        BAR;
        LOAD_A(nb, 0, a0)
        LOAD_B(nb, 0, b0)
        SB0;
        MM(1, 1, a1, b1)
    }

    // peeled last tile: drain remaining (A1 of last tile), nothing staged beyond
    {
        const int buf = (NT - 1) & 1;
        VMW("0");
        LOAD_B(buf, 1, b1)
        SB0;
        BAR;
        LGKM_B1;
        SB0;
        MM(0, 0, a0, b0)

        LOAD_A(buf, 1, a1)
        SB0;
        BAR;
        LGKM("8");
        SB0;
        MM(0, 1, a0, b1)

        BAR;
        LGKM("0");
        SB0;
        MM(1, 0, a1, b0)

        MM(1, 1, a1, b1)
    }

    const int cc = lane & 15, rr = (lane >> 4) << 2;
#pragma unroll
    for (int q = 0; q < 2; q++)
#pragma unroll
        for (int r2 = 0; r2 < 2; r2++)
#pragma unroll
            for (int m = 0; m < 4; m++)
#pragma unroll
                for (int n = 0; n < NB; n++) {
                    const int colG = bn * (NB * 128) + r2 * (NB * 64) + wn * (NB * 16) + n * 16 + cc;
                    const int rowG = bm * 256 + q * 128 + wm * 64 + m * 16 + rr;
                    const float bv = bias[colG];
#pragma unroll
                    for (int reg = 0; reg < 4; reg++) {
                        float v = acc[q][r2][m][n][reg] + bv;
                        v = fmaxf(v, 0.0f);
                        Cg[(size_t)(rowG + reg) * N + colG] = (__bf16)v;
                    }
                }
#undef STAGE_A
#undef STAGE_B
#undef LDFA
#undef LDFB
#undef LOAD_A
#undef LOAD_B
#undef MM
#undef SB0
#undef BAR
#undef LGKM_B1
#undef LGKM
#undef VMW
#undef VMW2
}

// ---------------- head: out[b,j] = h2[b,:] . Wq3[:,j] + bq3[j], j<3, K=512 ----------------
__global__ __launch_bounds__(256) void head_kernel(const __bf16* __restrict__ h2,
                                                   const float* __restrict__ Wq3,
                                                   const float* __restrict__ bq3,
                                                   float* __restrict__ out) {
    const int wave = threadIdx.x >> 6, lane = threadIdx.x & 63;
    const int row = blockIdx.x * 4 + wave;
    const bf16x8 hv = *(const bf16x8*)(h2 + (size_t)row * 512 + lane * 8);
    float s0 = 0.f, s1 = 0.f, s2 = 0.f;
#pragma unroll
    for (int i = 0; i < 8; i++) {
        const float hf = (float)hv[i];
        const int k = lane * 8 + i;
        s0 += hf * Wq3[k * 3 + 0];
        s1 += hf * Wq3[k * 3 + 1];
        s2 += hf * Wq3[k * 3 + 2];
    }
#pragma unroll
    for (int off = 32; off > 0; off >>= 1) {
        s0 += __shfl_xor(s0, off);
        s1 += __shfl_xor(s1, off);
        s2 += __shfl_xor(s2, off);
    }
    if (lane == 0) {
        float* o = out + (size_t)row * 3;
        o[0] = s0 + bq3[0];
        o[1] = s1 + bq3[1];
        o[2] = s2 + bq3[2];
    }
}

extern "C" void kernel_launch(void* const* d_in, const int* in_sizes, int n_in,
                              void* d_out, int out_size, void* d_ws, size_t ws_size,
                              hipStream_t stream) {
    const float* obs = (const float*)d_in[0];
    const float* act = (const float*)d_in[1];
    const float* Wp1 = (const float*)d_in[2];  const float* bp1 = (const float*)d_in[3];
    const float* Wp2 = (const float*)d_in[4];  const float* bp2 = (const float*)d_in[5];
    const float* Wt1 = (const float*)d_in[6];  const float* bt1 = (const float*)d_in[7];
    const float* Wt2 = (const float*)d_in[8];  const float* bt2 = (const float*)d_in[9];
    const float* Wr1 = (const float*)d_in[10]; const float* br1 = (const float*)d_in[11];
    const float* Wr2 = (const float*)d_in[12]; const float* br2 = (const float*)d_in[13];
    const float* Wq1 = (const float*)d_in[14]; const float* bq1 = (const float*)d_in[15];
    const float* Wq2 = (const float*)d_in[16]; const float* bq2 = (const float*)d_in[17];
    const float* Wq3 = (const float*)d_in[18]; const float* bq3 = (const float*)d_in[19];
    float* out = (float*)d_out;

    char* ws = (char*)d_ws;
    __bf16* enc = (__bf16*)(ws);                            // 88,080,384
    __bf16* h1  = (__bf16*)(ws + 88080384);                 // 33,554,432
    __bf16* h2  = (__bf16*)(ws + 88080384 + 33554432);      // 16,777,216
    __bf16* w1t = (__bf16*)(ws + 138412032);                // 5,505,024
    __bf16* w2t = (__bf16*)(ws + 143917056);                // 1,048,576
    float*  w1p = (float*)(ws + 144965632);                 // 17,664
    __bf16* w2e = (__bf16*)(ws + 144983296);                // 57,344

    // weight prep
    pack_weights<<<14, 256, 0, stream>>>(Wp1, bp1, Wp2, bp2, Wt1, bt1, Wt2, bt2,
                                         Wr1, br1, Wr2, br2, w1p, w2e);
    transpose_bf16_k<<<dim3(2688 / 64, 1024 / 64), 256, 0, stream>>>(Wq1, w1t, 2688, 1024);
    transpose_bf16_k<<<dim3(1024 / 64, 512 / 64), 256, 0, stream>>>(Wq2, w2t, 1024, 512);

    // fused encoders: 49152 rows, 192 rows/block, 256 blocks
    enc_fused<<<256, 192, 0, stream>>>(obs, act, w1p, w2e, enc);

    // q head
    gemm256_relu<2><<<dim3(256), 512, 0, stream>>>(enc, w1t, bq1, h1, 1024, 2688, 2);
    gemm256_relu<1><<<dim3(256), 512, 0, stream>>>(h1, w2t, bq2, h2, 512, 1024, 2);
    head_kernel<<<16384 / 4, 256, 0, stream>>>(h2, Wq3, bq3, out);
}

// Round 9
// 153.825 us; speedup vs baseline: 1.6144x; 1.0533x over previous
//
#include <hip/hip_runtime.h>
#include <hip/hip_bf16.h>
#include <cstdint>

typedef __bf16 bf16x8 __attribute__((ext_vector_type(8)));
typedef float f32x4 __attribute__((ext_vector_type(4)));

// ---------------- async global->LDS (16B per lane) ----------------
__device__ __forceinline__ void gld16(const __bf16* g, __bf16* lds) {
    __builtin_amdgcn_global_load_lds(
        (__attribute__((address_space(1))) void*)(uintptr_t)g,
        (__attribute__((address_space(3))) void*)(uint32_t)(uintptr_t)lds,
        16, 0, 0);
}

// ---------------- transpose + f32->bf16 convert: out[C][R] = in[R][C] ----------------
__global__ __launch_bounds__(256) void transpose_bf16_k(const float* __restrict__ in,
                                                        __bf16* __restrict__ out,
                                                        int R, int C) {
    __shared__ float t[64][65];
    const int r0 = blockIdx.x * 64, c0 = blockIdx.y * 64;
    const int tid = threadIdx.x;
#pragma unroll
    for (int i = 0; i < 16; i++) {
        int idx = i * 256 + tid;
        int rr = idx >> 6, cc = idx & 63;
        t[rr][cc] = in[(size_t)(r0 + rr) * C + (c0 + cc)];
    }
    __syncthreads();
#pragma unroll
    for (int i = 0; i < 16; i++) {
        int idx = i * 256 + tid;
        int rr = idx >> 6, cc = idx & 63;
        out[(size_t)(c0 + rr) * R + (r0 + cc)] = (__bf16)t[cc][rr];
    }
}

// ---------------- weight packing for fused encoder ----------------
__global__ __launch_bounds__(256) void pack_weights(const float* __restrict__ Wp1, const float* __restrict__ bp1,
                                                    const float* __restrict__ Wp2, const float* __restrict__ bp2,
                                                    const float* __restrict__ Wt1, const float* __restrict__ bt1,
                                                    const float* __restrict__ Wt2, const float* __restrict__ bt2,
                                                    const float* __restrict__ Wr1, const float* __restrict__ br1,
                                                    const float* __restrict__ Wr2, const float* __restrict__ br2,
                                                    float* __restrict__ w1p, __bf16* __restrict__ w2t) {
    const int s = blockIdx.x, tid = threadIdx.x;
    int ks, din, w1off;
    const float *W1, *B1, *W2, *B2;
    if (s < 9)      { ks = s;      din = 5;  w1off = s * 160;
                      W1 = Wp1; B1 = bp1; W2 = Wp2; B2 = bp2; }
    else if (s < 11){ ks = s - 9;  din = 12; w1off = 1440 + ks * 384;
                      W1 = Wt1; B1 = bt1; W2 = Wt2; B2 = bt2; }
    else            { ks = s - 11; din = 9;  w1off = 2208 + ks * 288;
                      W1 = Wr1; B1 = br1; W2 = Wr2; B2 = br2; }
    W1 += ks * din * 32; B1 += ks * 32; W2 += ks * 2048; B2 += ks * 64;
    for (int i = tid; i < din * 32; i += 256) w1p[w1off + i] = W1[i];
    if (tid < 32) w1p[3072 + s * 32 + tid] = B1[tid];
    if (tid < 64) w1p[3520 + s * 64 + tid] = B2[tid];
    for (int i = tid; i < 2048; i += 256) {
        const int o = i >> 5, k = i & 31;
        w2t[s * 2048 + i] = (__bf16)W2[k * 64 + o];
    }
}

// ---------------- fused encoder v2: 64 rows/block, 4 waves, 3 blocks/CU ----------------
// L1: 4 threads/row, each computes 8 h-values (f32 VALU). L2: per wave one 16-row
// A-frag from LDS + 4 B-frags from L2-hot w2t, 4 MFMA/segment. 768 blocks.
__global__ __launch_bounds__(256) void enc_fused(const float* __restrict__ obs,
                                                 const float* __restrict__ act,
                                                 const float* __restrict__ w1p,
                                                 const __bf16* __restrict__ w2t,
                                                 __bf16* __restrict__ enc) {
    __shared__ float sW[4416];             // [3072 W1][448 b1][896 b2]
    __shared__ __bf16 sH[2][64 * 40];      // dbuf h tiles (64 rows, stride 40)
    const int tid = threadIdx.x;
    for (int i = tid; i < 4416; i += 256) sW[i] = w1p[i];
    const int rloc = tid >> 2, q = tid & 3;   // row-in-block, h-quarter
    const int row = blockIdx.x * 64 + rloc;
    const float* orow = obs + (size_t)row * 144;
    const float a0 = act[row * 3], a1 = act[row * 3 + 1], a2 = act[row * 3 + 2];
    const int wv = tid >> 6, lane = tid & 63;
    const int fr = lane & 15, kq = lane >> 4;
    __syncthreads();
    int buf = 0;

    auto l2 = [&](int s) {
        __syncthreads();
        bf16x8 bfr[4];
#pragma unroll
        for (int n = 0; n < 4; n++)
            bfr[n] = *(const bf16x8*)&w2t[(s * 64 + n * 16 + fr) * 32 + kq * 8];
        const bf16x8 afr = *(const bf16x8*)&sH[buf][(wv * 16 + fr) * 40 + kq * 8];
        f32x4 acc[4] = {};
#pragma unroll
        for (int n = 0; n < 4; n++)
            acc[n] = __builtin_amdgcn_mfma_f32_16x16x32_bf16(afr, bfr[n], acc[n], 0, 0, 0);
        const float* b2 = sW + 3520 + s * 64;
        const size_t rG = (size_t)blockIdx.x * 64 + wv * 16 + kq * 4;
#pragma unroll
        for (int n = 0; n < 4; n++) {
            const float bv = b2[n * 16 + fr];
#pragma unroll
            for (int rg = 0; rg < 4; rg++) {
                float v = acc[n][rg] + bv;
                v = fmaxf(v, 0.01f * v);
                enc[(rG + rg) * 896 + s * 64 + n * 16 + fr] = (__bf16)v;
            }
        }
        buf ^= 1;
    };

#define L1(DIN, W1OFF, SGI, XLOAD)                                   \
    {                                                                \
        float x[DIN];                                                \
        XLOAD;                                                       \
        const float* w1 = sW + (W1OFF);                              \
        const float* b1 = sW + 3072 + (SGI) * 32;                    \
        bf16x8 t_;                                                   \
        _Pragma("unroll") for (int j = 0; j < 8; j++) {              \
            const int o = q * 8 + j;                                 \
            float a_ = b1[o];                                        \
            _Pragma("unroll") for (int i = 0; i < DIN; i++)          \
                a_ += x[i] * w1[i * 32 + o];                         \
            t_[j] = (__bf16)fmaxf(a_, 0.01f * a_);                   \
        }                                                            \
        *(bf16x8*)&sH[buf][rloc * 40 + q * 8] = t_;                  \
    }

    for (int k = 0; k < 9; k++) {
        L1(5, k * 160, k,
           { x[0] = orow[2 * k]; x[1] = orow[2 * k + 1]; x[2] = a0; x[3] = a1; x[4] = a2; })
        l2(k);
    }
    for (int k = 0; k < 2; k++) {
        L1(12, 1440 + k * 384, 9 + k,
           { _Pragma("unroll") for (int i = 0; i < 12; i++) x[i] = orow[18 + 12 * k + i]; })
        l2(9 + k);
    }
    for (int k = 0; k < 3; k++) {
        L1(9, 2208 + k * 288, 11 + k,
           { _Pragma("unroll") for (int i = 0; i < 9; i++) x[i] = orow[117 + 9 * k + i]; })
        l2(11 + k);
    }
#undef L1
}

// ---------------- 256xBN bf16 GEMM: balanced counted-vmcnt pipeline ----------------
// Reads: W1=B1(4|2), W2=A1(8), W3=A0'(8), W4=B0'(4|2). Stages: W1=A0',B0'; W2=B1',A1'.
// vm ledger (FIFO): enter W1 = [A1]=2; W1 +4|3, VMW(4|3) drains A1; W2 +4|3;
// W3 VMW(2) drains A0',B0',B1' (covers W3/W4/next-W1 reads); leaves A1'=2.
// lgkm: W1 wait 4|2 (a0,b0 done); W2 wait 8 (b1 done); W3 wait 8 (a1 done).
// End-barrier after every MFMA cluster (m201 2-barrier phase).
template <int NB>
__global__ __launch_bounds__(512, 2) void gemm256_relu(const __bf16* __restrict__ Ag,
                                                       const __bf16* __restrict__ Btg,
                                                       const float* __restrict__ bias,
                                                       __bf16* __restrict__ Cg,
                                                       int N, int K, int lgn) {
    __shared__ __align__(16) __bf16 ldsA[2][2][128 * 64];
    __shared__ __align__(16) __bf16 ldsB[2][2][NB * 64 * 64];
    const int tid = threadIdx.x;
    const int wid = tid >> 6, lane = tid & 63;
    const int wm = wid >> 2, wn = wid & 3;
    const int fr = lane & 15, kq = lane >> 4;

    const int chunk = gridDim.x >> 3;
    const int wg = (blockIdx.x & 7) * chunk + (blockIdx.x >> 3);
    const int bn = wg & ((1 << lgn) - 1), bm = wg >> lgn;

    const int c0 = tid, c1 = tid + 512;
    const int r0 = c0 >> 3, s0 = (c0 & 7) ^ (r0 & 7);
    const int r1 = c1 >> 3, s1 = (c1 & 7) ^ (r1 & 7);
    const size_t aH = (size_t)128 * K;
    const size_t bH = (size_t)(NB * 64) * K;
    const __bf16* aB0 = Ag + (size_t)(bm * 256 + r0) * K + s0 * 8;
    const __bf16* aB1 = Ag + (size_t)(bm * 256 + r1) * K + s1 * 8;
    const __bf16* bB0 = Btg + (size_t)(bn * (NB * 128) + r0) * K + s0 * 8;
    const __bf16* bB1 = Btg + (size_t)(bn * (NB * 128) + r1) * K + s1 * 8;

    f32x4 acc[2][2][4][NB] = {};
    bf16x8 a0[4][2], a1[4][2], b0[NB][2], b1[NB][2];

#define STAGE_A(BUF, H, KO)                                   \
    do {                                                      \
        __bf16* d_ = &ldsA[BUF][H][0];                        \
        gld16(aB0 + (H)*aH + (KO), d_ + c0 * 8);              \
        gld16(aB1 + (H)*aH + (KO), d_ + c1 * 8);              \
    } while (0)
#define STAGE_B(BUF, H, KO)                                   \
    do {                                                      \
        __bf16* d_ = &ldsB[BUF][H][0];                        \
        gld16(bB0 + (H)*bH + (KO), d_ + c0 * 8);              \
        if constexpr (NB == 2) gld16(bB1 + (H)*bH + (KO), d_ + c1 * 8); \
    } while (0)

#define LDFA(BUF, H, ROW, KS) \
    (*(const bf16x8*)&ldsA[BUF][H][(ROW) * 64 + ((((KS)*4 + kq) ^ ((ROW)&7)) * 8)])
#define LDFB(BUF, H, ROW, KS) \
    (*(const bf16x8*)&ldsB[BUF][H][(ROW) * 64 + ((((KS)*4 + kq) ^ ((ROW)&7)) * 8)])

#define LOAD_A(BUF, H, DST)                                   \
    _Pragma("unroll") for (int m = 0; m < 4; m++)             \
        _Pragma("unroll") for (int ks = 0; ks < 2; ks++)      \
            DST[m][ks] = LDFA(BUF, H, wm * 64 + m * 16 + fr, ks);
#define LOAD_B(BUF, H, DST)                                   \
    _Pragma("unroll") for (int n = 0; n < NB; n++)            \
        _Pragma("unroll") for (int ks = 0; ks < 2; ks++)      \
            DST[n][ks] = LDFB(BUF, H, wn * (NB * 16) + n * 16 + fr, ks);

#define MM(Q, R, AR, BR)                                      \
    __builtin_amdgcn_s_setprio(1);                            \
    _Pragma("unroll") for (int ks = 0; ks < 2; ks++)          \
        _Pragma("unroll") for (int m = 0; m < 4; m++)         \
            _Pragma("unroll") for (int n = 0; n < NB; n++)    \
                acc[Q][R][m][n] = __builtin_amdgcn_mfma_f32_16x16x32_bf16( \
                    AR[m][ks], BR[n][ks], acc[Q][R][m][n], 0, 0, 0); \
    __builtin_amdgcn_s_setprio(0);

#define SB0 __builtin_amdgcn_sched_barrier(0)
#define BAR __builtin_amdgcn_s_barrier()
#define LGKM(NSTR) asm volatile("s_waitcnt lgkmcnt(" NSTR ")" ::: "memory")
#define LGKM2(N2, N1)                                         \
    if constexpr (NB == 2) LGKM(#N2); else LGKM(#N1);
#define VMW(NSTR) asm volatile("s_waitcnt vmcnt(" NSTR ")" ::: "memory")
#define VMW2(N2, N1)                                          \
    if constexpr (NB == 2) VMW(#N2); else VMW(#N1);

    const int NT = K >> 6;

    // prologue: stage tile 0 (A0,B0,B1,A1); cover all but A1
    STAGE_A(0, 0, 0);
    STAGE_B(0, 0, 0);
    STAGE_B(0, 1, 0);
    STAGE_A(0, 1, 0);
    VMW("2");
    BAR;
    LOAD_A(0, 0, a0)
    LOAD_B(0, 0, b0)
    SB0;

    for (int t = 0; t < NT - 1; ++t) {
        const int buf = t & 1, nb = buf ^ 1;
        const int kO = (t + 1) << 6;

        // W1: Q(0,0)
        STAGE_A(nb, 0, kO);
        STAGE_B(nb, 0, kO);
        VMW2(4, 3);               // drain A1(t)
        LOAD_B(buf, 1, b1)        // B1(t): covered by W3(t-1) VMW(2)+BAR
        SB0;
        BAR;
        LGKM2(4, 2);              // a0,b0 ready (b1 in flight)
        SB0;
        MM(0, 0, a0, b0)
        BAR;

        // W2: Q(0,1)
        STAGE_B(nb, 1, kO);
        STAGE_A(nb, 1, kO);
        LOAD_A(buf, 1, a1)        // A1(t): covered by W1 VMW2+BAR
        SB0;
        BAR;
        LGKM("8");                // b1 ready (a1 in flight)
        SB0;
        MM(0, 1, a0, b1)
        BAR;

        // W3: Q(1,0)
        VMW("2");                 // drain A0',B0',B1' (leaves A1')
        SB0;
        BAR;
        LOAD_A(nb, 0, a0)         // next-tile A0 (covered by this BAR)
        SB0;
        LGKM("8");                // a1 ready (a0' reads in flight)
        SB0;
        MM(1, 0, a1, b0)
        BAR;

        // W4: Q(1,1)
        LOAD_B(nb, 0, b0)         // next-tile B0 (covered by W3 BAR)
        SB0;
        MM(1, 1, a1, b1)
        BAR;
    }

    // peeled last tile
    {
        const int buf = (NT - 1) & 1;
        VMW("0");                 // drain A1 of last tile
        LOAD_B(buf, 1, b1)
        SB0;
        BAR;
        LGKM2(4, 2);
        SB0;
        MM(0, 0, a0, b0)
        BAR;

        LOAD_A(buf, 1, a1)
        SB0;
        BAR;
        LGKM("8");
        SB0;
        MM(0, 1, a0, b1)
        BAR;

        LGKM("0");
        SB0;
        MM(1, 0, a1, b0)
        MM(1, 1, a1, b1)
    }

    const int cc = lane & 15, rr = (lane >> 4) << 2;
#pragma unroll
    for (int q = 0; q < 2; q++)
#pragma unroll
        for (int r2 = 0; r2 < 2; r2++)
#pragma unroll
            for (int m = 0; m < 4; m++)
#pragma unroll
                for (int n = 0; n < NB; n++) {
                    const int colG = bn * (NB * 128) + r2 * (NB * 64) + wn * (NB * 16) + n * 16 + cc;
                    const int rowG = bm * 256 + q * 128 + wm * 64 + m * 16 + rr;
                    const float bv = bias[colG];
#pragma unroll
                    for (int reg = 0; reg < 4; reg++) {
                        float v = acc[q][r2][m][n][reg] + bv;
                        v = fmaxf(v, 0.0f);
                        Cg[(size_t)(rowG + reg) * N + colG] = (__bf16)v;
                    }
                }
#undef STAGE_A
#undef STAGE_B
#undef LDFA
#undef LDFB
#undef LOAD_A
#undef LOAD_B
#undef MM
#undef SB0
#undef BAR
#undef LGKM
#undef LGKM2
#undef VMW
#undef VMW2
}

// ---------------- head: out[b,j] = h2[b,:] . Wq3[:,j] + bq3[j], j<3, K=512 ----------------
__global__ __launch_bounds__(256) void head_kernel(const __bf16* __restrict__ h2,
                                                   const float* __restrict__ Wq3,
                                                   const float* __restrict__ bq3,
                                                   float* __restrict__ out) {
    const int wave = threadIdx.x >> 6, lane = threadIdx.x & 63;
    const int row = blockIdx.x * 4 + wave;
    const bf16x8 hv = *(const bf16x8*)(h2 + (size_t)row * 512 + lane * 8);
    float s0 = 0.f, s1 = 0.f, s2 = 0.f;
#pragma unroll
    for (int i = 0; i < 8; i++) {
        const float hf = (float)hv[i];
        const int k = lane * 8 + i;
        s0 += hf * Wq3[k * 3 + 0];
        s1 += hf * Wq3[k * 3 + 1];
        s2 += hf * Wq3[k * 3 + 2];
    }
#pragma unroll
    for (int off = 32; off > 0; off >>= 1) {
        s0 += __shfl_xor(s0, off);
        s1 += __shfl_xor(s1, off);
        s2 += __shfl_xor(s2, off);
    }
    if (lane == 0) {
        float* o = out + (size_t)row * 3;
        o[0] = s0 + bq3[0];
        o[1] = s1 + bq3[1];
        o[2] = s2 + bq3[2];
    }
}

extern "C" void kernel_launch(void* const* d_in, const int* in_sizes, int n_in,
                              void* d_out, int out_size, void* d_ws, size_t ws_size,
                              hipStream_t stream) {
    const float* obs = (const float*)d_in[0];
    const float* act = (const float*)d_in[1];
    const float* Wp1 = (const float*)d_in[2];  const float* bp1 = (const float*)d_in[3];
    const float* Wp2 = (const float*)d_in[4];  const float* bp2 = (const float*)d_in[5];
    const float* Wt1 = (const float*)d_in[6];  const float* bt1 = (const float*)d_in[7];
    const float* Wt2 = (const float*)d_in[8];  const float* bt2 = (const float*)d_in[9];
    const float* Wr1 = (const float*)d_in[10]; const float* br1 = (const float*)d_in[11];
    const float* Wr2 = (const float*)d_in[12]; const float* br2 = (const float*)d_in[13];
    const float* Wq1 = (const float*)d_in[14]; const float* bq1 = (const float*)d_in[15];
    const float* Wq2 = (const float*)d_in[16]; const float* bq2 = (const float*)d_in[17];
    const float* Wq3 = (const float*)d_in[18]; const float* bq3 = (const float*)d_in[19];
    float* out = (float*)d_out;

    char* ws = (char*)d_ws;
    __bf16* enc = (__bf16*)(ws);                            // 88,080,384
    __bf16* h1  = (__bf16*)(ws + 88080384);                 // 33,554,432
    __bf16* h2  = (__bf16*)(ws + 88080384 + 33554432);      // 16,777,216
    __bf16* w1t = (__bf16*)(ws + 138412032);                // 5,505,024
    __bf16* w2t = (__bf16*)(ws + 143917056);                // 1,048,576
    float*  w1p = (float*)(ws + 144965632);                 // 17,664
    __bf16* w2e = (__bf16*)(ws + 144983296);                // 57,344

    // weight prep
    pack_weights<<<14, 256, 0, stream>>>(Wp1, bp1, Wp2, bp2, Wt1, bt1, Wt2, bt2,
                                         Wr1, br1, Wr2, br2, w1p, w2e);
    transpose_bf16_k<<<dim3(2688 / 64, 1024 / 64), 256, 0, stream>>>(Wq1, w1t, 2688, 1024);
    transpose_bf16_k<<<dim3(1024 / 64, 512 / 64), 256, 0, stream>>>(Wq2, w2t, 1024, 512);

    // fused encoders: 49152 rows, 64 rows/block, 768 blocks (3/CU)
    enc_fused<<<768, 256, 0, stream>>>(obs, act, w1p, w2e, enc);

    // q head
    gemm256_relu<2><<<dim3(256), 512, 0, stream>>>(enc, w1t, bq1, h1, 1024, 2688, 2);
    gemm256_relu<1><<<dim3(256), 512, 0, stream>>>(h1, w2t, bq2, h2, 512, 1024, 2);
    head_kernel<<<16384 / 4, 256, 0, stream>>>(h2, Wq3, bq3, out);
}

// Round 10
// 146.941 us; speedup vs baseline: 1.6901x; 1.0468x over previous
//
#include <hip/hip_runtime.h>
#include <hip/hip_bf16.h>
#include <cstdint>

typedef __bf16 bf16x8 __attribute__((ext_vector_type(8)));
typedef float f32x4 __attribute__((ext_vector_type(4)));

// ---------------- async global->LDS (16B per lane) ----------------
__device__ __forceinline__ void gld16(const __bf16* g, __bf16* lds) {
    __builtin_amdgcn_global_load_lds(
        (__attribute__((address_space(1))) void*)(uintptr_t)g,
        (__attribute__((address_space(3))) void*)(uint32_t)(uintptr_t)lds,
        16, 0, 0);
}

// ---------------- transpose + f32->bf16 convert: out[C][R] = in[R][C] ----------------
__global__ __launch_bounds__(256) void transpose_bf16_k(const float* __restrict__ in,
                                                        __bf16* __restrict__ out,
                                                        int R, int C) {
    __shared__ float t[64][65];
    const int r0 = blockIdx.x * 64, c0 = blockIdx.y * 64;
    const int tid = threadIdx.x;
#pragma unroll
    for (int i = 0; i < 16; i++) {
        int idx = i * 256 + tid;
        int rr = idx >> 6, cc = idx & 63;
        t[rr][cc] = in[(size_t)(r0 + rr) * C + (c0 + cc)];
    }
    __syncthreads();
#pragma unroll
    for (int i = 0; i < 16; i++) {
        int idx = i * 256 + tid;
        int rr = idx >> 6, cc = idx & 63;
        out[(size_t)(c0 + rr) * R + (r0 + cc)] = (__bf16)t[cc][rr];
    }
}

// ---------------- weight packing for fused encoder ----------------
__global__ __launch_bounds__(256) void pack_weights(const float* __restrict__ Wp1, const float* __restrict__ bp1,
                                                    const float* __restrict__ Wp2, const float* __restrict__ bp2,
                                                    const float* __restrict__ Wt1, const float* __restrict__ bt1,
                                                    const float* __restrict__ Wt2, const float* __restrict__ bt2,
                                                    const float* __restrict__ Wr1, const float* __restrict__ br1,
                                                    const float* __restrict__ Wr2, const float* __restrict__ br2,
                                                    float* __restrict__ w1p, __bf16* __restrict__ w2t) {
    const int s = blockIdx.x, tid = threadIdx.x;
    int ks, din, w1off;
    const float *W1, *B1, *W2, *B2;
    if (s < 9)      { ks = s;      din = 5;  w1off = s * 160;
                      W1 = Wp1; B1 = bp1; W2 = Wp2; B2 = bp2; }
    else if (s < 11){ ks = s - 9;  din = 12; w1off = 1440 + ks * 384;
                      W1 = Wt1; B1 = bt1; W2 = Wt2; B2 = bt2; }
    else            { ks = s - 11; din = 9;  w1off = 2208 + ks * 288;
                      W1 = Wr1; B1 = br1; W2 = Wr2; B2 = br2; }
    W1 += ks * din * 32; B1 += ks * 32; W2 += ks * 2048; B2 += ks * 64;
    for (int i = tid; i < din * 32; i += 256) w1p[w1off + i] = W1[i];
    if (tid < 32) w1p[3072 + s * 32 + tid] = B1[tid];
    if (tid < 64) w1p[3520 + s * 64 + tid] = B2[tid];
    for (int i = tid; i < 2048; i += 256) {
        const int o = i >> 5, k = i & 31;
        w2t[s * 2048 + i] = (__bf16)W2[k * 64 + o];
    }
}

// ---------------- fused encoder v2: 64 rows/block, 4 waves, 3 blocks/CU ----------------
__global__ __launch_bounds__(256) void enc_fused(const float* __restrict__ obs,
                                                 const float* __restrict__ act,
                                                 const float* __restrict__ w1p,
                                                 const __bf16* __restrict__ w2t,
                                                 __bf16* __restrict__ enc) {
    __shared__ float sW[4416];             // [3072 W1][448 b1][896 b2]
    __shared__ __bf16 sH[2][64 * 40];      // dbuf h tiles (64 rows, stride 40)
    const int tid = threadIdx.x;
    for (int i = tid; i < 4416; i += 256) sW[i] = w1p[i];
    const int rloc = tid >> 2, q = tid & 3;   // row-in-block, h-quarter
    const int row = blockIdx.x * 64 + rloc;
    const float* orow = obs + (size_t)row * 144;
    const float a0 = act[row * 3], a1 = act[row * 3 + 1], a2 = act[row * 3 + 2];
    const int wv = tid >> 6, lane = tid & 63;
    const int fr = lane & 15, kq = lane >> 4;
    __syncthreads();
    int buf = 0;

    auto l2 = [&](int s) {
        __syncthreads();
        bf16x8 bfr[4];
#pragma unroll
        for (int n = 0; n < 4; n++)
            bfr[n] = *(const bf16x8*)&w2t[(s * 64 + n * 16 + fr) * 32 + kq * 8];
        const bf16x8 afr = *(const bf16x8*)&sH[buf][(wv * 16 + fr) * 40 + kq * 8];
        f32x4 acc[4] = {};
#pragma unroll
        for (int n = 0; n < 4; n++)
            acc[n] = __builtin_amdgcn_mfma_f32_16x16x32_bf16(afr, bfr[n], acc[n], 0, 0, 0);
        const float* b2 = sW + 3520 + s * 64;
        const size_t rG = (size_t)blockIdx.x * 64 + wv * 16 + kq * 4;
#pragma unroll
        for (int n = 0; n < 4; n++) {
            const float bv = b2[n * 16 + fr];
#pragma unroll
            for (int rg = 0; rg < 4; rg++) {
                float v = acc[n][rg] + bv;
                v = fmaxf(v, 0.01f * v);
                enc[(rG + rg) * 896 + s * 64 + n * 16 + fr] = (__bf16)v;
            }
        }
        buf ^= 1;
    };

#define L1(DIN, W1OFF, SGI, XLOAD)                                   \
    {                                                                \
        float x[DIN];                                                \
        XLOAD;                                                       \
        const float* w1 = sW + (W1OFF);                              \
        const float* b1 = sW + 3072 + (SGI) * 32;                    \
        bf16x8 t_;                                                   \
        _Pragma("unroll") for (int j = 0; j < 8; j++) {              \
            const int o = q * 8 + j;                                 \
            float a_ = b1[o];                                        \
            _Pragma("unroll") for (int i = 0; i < DIN; i++)          \
                a_ += x[i] * w1[i * 32 + o];                         \
            t_[j] = (__bf16)fmaxf(a_, 0.01f * a_);                   \
        }                                                            \
        *(bf16x8*)&sH[buf][rloc * 40 + q * 8] = t_;                  \
    }

    for (int k = 0; k < 9; k++) {
        L1(5, k * 160, k,
           { x[0] = orow[2 * k]; x[1] = orow[2 * k + 1]; x[2] = a0; x[3] = a1; x[4] = a2; })
        l2(k);
    }
    for (int k = 0; k < 2; k++) {
        L1(12, 1440 + k * 384, 9 + k,
           { _Pragma("unroll") for (int i = 0; i < 12; i++) x[i] = orow[18 + 12 * k + i]; })
        l2(9 + k);
    }
    for (int k = 0; k < 3; k++) {
        L1(9, 2208 + k * 288, 11 + k,
           { _Pragma("unroll") for (int i = 0; i < 9; i++) x[i] = orow[117 + 9 * k + i]; })
        l2(11 + k);
    }
#undef L1
}

// ---------------- 256xBN bf16 GEMM: counted-vmcnt pipeline (R8 schedule, validated) ----------------
// Cross-wave rule: every ds_read of a staged region follows a BARRIER that is preceded
// (in ALL waves) by a vmcnt wait covering that region's loads.
//   W1: stage A0',B0'; vmcnt(4|3)  -> covers A1(t)   [read at W2, after W1.BAR]
//   W2: stage B1',A1'; (no wait)
//   W4: vmcnt(2)                   -> covers A0',B0' [read at W4 after BAR] and B1'
//                                     [read at next W1, after W4.BAR]
// One barrier per phase (NOT two): with 1 block/CU the inter-wave phase drift is the
// only MFMA/LDS overlap source — end-barriers cost ~12% (measured R9).
template <int NB>
__global__ __launch_bounds__(512, 2) void gemm256_relu(const __bf16* __restrict__ Ag,
                                                       const __bf16* __restrict__ Btg,
                                                       const float* __restrict__ bias,
                                                       __bf16* __restrict__ Cg,
                                                       int N, int K, int lgn) {
    __shared__ __align__(16) __bf16 ldsA[2][2][128 * 64];
    __shared__ __align__(16) __bf16 ldsB[2][2][NB * 64 * 64];
    const int tid = threadIdx.x;
    const int wid = tid >> 6, lane = tid & 63;
    const int wm = wid >> 2, wn = wid & 3;
    const int fr = lane & 15, kq = lane >> 4;

    const int chunk = gridDim.x >> 3;
    const int wg = (blockIdx.x & 7) * chunk + (blockIdx.x >> 3);
    const int bn = wg & ((1 << lgn) - 1), bm = wg >> lgn;

    const int c0 = tid, c1 = tid + 512;
    const int r0 = c0 >> 3, s0 = (c0 & 7) ^ (r0 & 7);
    const int r1 = c1 >> 3, s1 = (c1 & 7) ^ (r1 & 7);
    const size_t aH = (size_t)128 * K;
    const size_t bH = (size_t)(NB * 64) * K;
    const __bf16* aB0 = Ag + (size_t)(bm * 256 + r0) * K + s0 * 8;
    const __bf16* aB1 = Ag + (size_t)(bm * 256 + r1) * K + s1 * 8;
    const __bf16* bB0 = Btg + (size_t)(bn * (NB * 128) + r0) * K + s0 * 8;
    const __bf16* bB1 = Btg + (size_t)(bn * (NB * 128) + r1) * K + s1 * 8;

    f32x4 acc[2][2][4][NB] = {};
    bf16x8 a0[4][2], a1[4][2], b0[NB][2], b1[NB][2];

#define STAGE_A(BUF, H, KO)                                   \
    do {                                                      \
        __bf16* d_ = &ldsA[BUF][H][0];                        \
        gld16(aB0 + (H)*aH + (KO), d_ + c0 * 8);              \
        gld16(aB1 + (H)*aH + (KO), d_ + c1 * 8);              \
    } while (0)
#define STAGE_B(BUF, H, KO)                                   \
    do {                                                      \
        __bf16* d_ = &ldsB[BUF][H][0];                        \
        gld16(bB0 + (H)*bH + (KO), d_ + c0 * 8);              \
        if constexpr (NB == 2) gld16(bB1 + (H)*bH + (KO), d_ + c1 * 8); \
    } while (0)

#define LDFA(BUF, H, ROW, KS) \
    (*(const bf16x8*)&ldsA[BUF][H][(ROW) * 64 + ((((KS)*4 + kq) ^ ((ROW)&7)) * 8)])
#define LDFB(BUF, H, ROW, KS) \
    (*(const bf16x8*)&ldsB[BUF][H][(ROW) * 64 + ((((KS)*4 + kq) ^ ((ROW)&7)) * 8)])

#define LOAD_A(BUF, H, DST)                                   \
    _Pragma("unroll") for (int m = 0; m < 4; m++)             \
        _Pragma("unroll") for (int ks = 0; ks < 2; ks++)      \
            DST[m][ks] = LDFA(BUF, H, wm * 64 + m * 16 + fr, ks);
#define LOAD_B(BUF, H, DST)                                   \
    _Pragma("unroll") for (int n = 0; n < NB; n++)            \
        _Pragma("unroll") for (int ks = 0; ks < 2; ks++)      \
            DST[n][ks] = LDFB(BUF, H, wn * (NB * 16) + n * 16 + fr, ks);

#define MM(Q, R, AR, BR)                                      \
    __builtin_amdgcn_s_setprio(1);                            \
    _Pragma("unroll") for (int ks = 0; ks < 2; ks++)          \
        _Pragma("unroll") for (int m = 0; m < 4; m++)         \
            _Pragma("unroll") for (int n = 0; n < NB; n++)    \
                acc[Q][R][m][n] = __builtin_amdgcn_mfma_f32_16x16x32_bf16( \
                    AR[m][ks], BR[n][ks], acc[Q][R][m][n], 0, 0, 0); \
    __builtin_amdgcn_s_setprio(0);

#define SB0 __builtin_amdgcn_sched_barrier(0)
#define BAR __builtin_amdgcn_s_barrier()
#define LGKM_B1                                               \
    if constexpr (NB == 2) asm volatile("s_waitcnt lgkmcnt(4)" ::: "memory"); \
    else asm volatile("s_waitcnt lgkmcnt(2)" ::: "memory");
#define LGKM(NSTR) asm volatile("s_waitcnt lgkmcnt(" NSTR ")" ::: "memory")
#define VMW(NSTR) asm volatile("s_waitcnt vmcnt(" NSTR ")" ::: "memory")
#define VMW2(N2, N1)                                          \
    if constexpr (NB == 2) VMW(#N2); else VMW(#N1);

    const int NT = K >> 6;

    // prologue: stage tile 0 (A0,B0,B1,A1); cover all but A1 (read at W2(0))
    STAGE_A(0, 0, 0);
    STAGE_B(0, 0, 0);
    STAGE_B(0, 1, 0);
    STAGE_A(0, 1, 0);
    VMW("2");
    BAR;
    LOAD_A(0, 0, a0)
    LOAD_B(0, 0, b0)
    SB0;

    for (int t = 0; t < NT - 1; ++t) {
        const int buf = t & 1, nb = buf ^ 1;
        const int kO = (t + 1) << 6;

        // W1: stage A0',B0'; vmcnt covers A1(t) (leaves A0',B0' in flight)
        STAGE_A(nb, 0, kO);
        STAGE_B(nb, 0, kO);
        VMW2(4, 3);
        LOAD_B(buf, 1, b1)        // B1(t): covered by W4(t-1) VMW("2") + BAR
        SB0;
        BAR;
        LGKM_B1;
        SB0;
        MM(0, 0, a0, b0)

        // W2: stage B1',A1'
        STAGE_B(nb, 1, kO);
        STAGE_A(nb, 1, kO);
        LOAD_A(buf, 1, a1)        // A1(t): covered by W1 VMW2(4,3) + BAR
        SB0;
        BAR;
        LGKM("8");
        SB0;
        MM(0, 1, a0, b1)

        // W3
        BAR;
        LGKM("0");
        SB0;
        MM(1, 0, a1, b0)

        // W4: cover A0',B0',B1' (leaves only A1' in flight)
        VMW("2");
        BAR;
        LOAD_A(nb, 0, a0)
        LOAD_B(nb, 0, b0)
        SB0;
        MM(1, 1, a1, b1)
    }

    // peeled last tile: drain remaining (A1 of last tile), nothing staged beyond
    {
        const int buf = (NT - 1) & 1;
        VMW("0");
        LOAD_B(buf, 1, b1)
        SB0;
        BAR;
        LGKM_B1;
        SB0;
        MM(0, 0, a0, b0)

        LOAD_A(buf, 1, a1)
        SB0;
        BAR;
        LGKM("8");
        SB0;
        MM(0, 1, a0, b1)

        BAR;
        LGKM("0");
        SB0;
        MM(1, 0, a1, b0)

        MM(1, 1, a1, b1)
    }

    const int cc = lane & 15, rr = (lane >> 4) << 2;
#pragma unroll
    for (int q = 0; q < 2; q++)
#pragma unroll
        for (int r2 = 0; r2 < 2; r2++)
#pragma unroll
            for (int m = 0; m < 4; m++)
#pragma unroll
                for (int n = 0; n < NB; n++) {
                    const int colG = bn * (NB * 128) + r2 * (NB * 64) + wn * (NB * 16) + n * 16 + cc;
                    const int rowG = bm * 256 + q * 128 + wm * 64 + m * 16 + rr;
                    const float bv = bias[colG];
#pragma unroll
                    for (int reg = 0; reg < 4; reg++) {
                        float v = acc[q][r2][m][n][reg] + bv;
                        v = fmaxf(v, 0.0f);
                        Cg[(size_t)(rowG + reg) * N + colG] = (__bf16)v;
                    }
                }
#undef STAGE_A
#undef STAGE_B
#undef LDFA
#undef LDFB
#undef LOAD_A
#undef LOAD_B
#undef MM
#undef SB0
#undef BAR
#undef LGKM_B1
#undef LGKM
#undef VMW
#undef VMW2
}

// ---------------- head: out[b,j] = h2[b,:] . Wq3[:,j] + bq3[j], j<3, K=512 ----------------
__global__ __launch_bounds__(256) void head_kernel(const __bf16* __restrict__ h2,
                                                   const float* __restrict__ Wq3,
                                                   const float* __restrict__ bq3,
                                                   float* __restrict__ out) {
    const int wave = threadIdx.x >> 6, lane = threadIdx.x & 63;
    const int row = blockIdx.x * 4 + wave;
    const bf16x8 hv = *(const bf16x8*)(h2 + (size_t)row * 512 + lane * 8);
    float s0 = 0.f, s1 = 0.f, s2 = 0.f;
#pragma unroll
    for (int i = 0; i < 8; i++) {
        const float hf = (float)hv[i];
        const int k = lane * 8 + i;
        s0 += hf * Wq3[k * 3 + 0];
        s1 += hf * Wq3[k * 3 + 1];
        s2 += hf * Wq3[k * 3 + 2];
    }
#pragma unroll
    for (int off = 32; off > 0; off >>= 1) {
        s0 += __shfl_xor(s0, off);
        s1 += __shfl_xor(s1, off);
        s2 += __shfl_xor(s2, off);
    }
    if (lane == 0) {
        float* o = out + (size_t)row * 3;
        o[0] = s0 + bq3[0];
        o[1] = s1 + bq3[1];
        o[2] = s2 + bq3[2];
    }
}

extern "C" void kernel_launch(void* const* d_in, const int* in_sizes, int n_in,
                              void* d_out, int out_size, void* d_ws, size_t ws_size,
                              hipStream_t stream) {
    const float* obs = (const float*)d_in[0];
    const float* act = (const float*)d_in[1];
    const float* Wp1 = (const float*)d_in[2];  const float* bp1 = (const float*)d_in[3];
    const float* Wp2 = (const float*)d_in[4];  const float* bp2 = (const float*)d_in[5];
    const float* Wt1 = (const float*)d_in[6];  const float* bt1 = (const float*)d_in[7];
    const float* Wt2 = (const float*)d_in[8];  const float* bt2 = (const float*)d_in[9];
    const float* Wr1 = (const float*)d_in[10]; const float* br1 = (const float*)d_in[11];
    const float* Wr2 = (const float*)d_in[12]; const float* br2 = (const float*)d_in[13];
    const float* Wq1 = (const float*)d_in[14]; const float* bq1 = (const float*)d_in[15];
    const float* Wq2 = (const float*)d_in[16]; const float* bq2 = (const float*)d_in[17];
    const float* Wq3 = (const float*)d_in[18]; const float* bq3 = (const float*)d_in[19];
    float* out = (float*)d_out;

    char* ws = (char*)d_ws;
    __bf16* enc = (__bf16*)(ws);                            // 88,080,384
    __bf16* h1  = (__bf16*)(ws + 88080384);                 // 33,554,432
    __bf16* h2  = (__bf16*)(ws + 88080384 + 33554432);      // 16,777,216
    __bf16* w1t = (__bf16*)(ws + 138412032);                // 5,505,024
    __bf16* w2t = (__bf16*)(ws + 143917056);                // 1,048,576
    float*  w1p = (float*)(ws + 144965632);                 // 17,664
    __bf16* w2e = (__bf16*)(ws + 144983296);                // 57,344

    // weight prep
    pack_weights<<<14, 256, 0, stream>>>(Wp1, bp1, Wp2, bp2, Wt1, bt1, Wt2, bt2,
                                         Wr1, br1, Wr2, br2, w1p, w2e);
    transpose_bf16_k<<<dim3(2688 / 64, 1024 / 64), 256, 0, stream>>>(Wq1, w1t, 2688, 1024);
    transpose_bf16_k<<<dim3(1024 / 64, 512 / 64), 256, 0, stream>>>(Wq2, w2t, 1024, 512);

    // fused encoders: 49152 rows, 64 rows/block, 768 blocks (3/CU)
    enc_fused<<<768, 256, 0, stream>>>(obs, act, w1p, w2e, enc);

    // q head
    gemm256_relu<2><<<dim3(256), 512, 0, stream>>>(enc, w1t, bq1, h1, 1024, 2688, 2);
    gemm256_relu<1><<<dim3(256), 512, 0, stream>>>(h1, w2t, bq2, h2, 512, 1024, 2);
    head_kernel<<<16384 / 4, 256, 0, stream>>>(h2, Wq3, bq3, out);
}

// Round 11
// 137.803 us; speedup vs baseline: 1.8021x; 1.0663x over previous
//
#include <hip/hip_runtime.h>
#include <hip/hip_bf16.h>
#include <cstdint>

typedef __bf16 bf16x8 __attribute__((ext_vector_type(8)));
typedef float f32x4 __attribute__((ext_vector_type(4)));

// ---------------- async global->LDS (16B per lane) ----------------
__device__ __forceinline__ void gld16(const __bf16* g, __bf16* lds) {
    __builtin_amdgcn_global_load_lds(
        (__attribute__((address_space(1))) void*)(uintptr_t)g,
        (__attribute__((address_space(3))) void*)(uint32_t)(uintptr_t)lds,
        16, 0, 0);
}

// ---------------- fused weight prep: T(Wq1), T(Wq2), encoder pack — one launch ----------------
// blocks 0..671: Wq1 [2688x1024] -> w1t [1024][2688] bf16  (42 x 16 tiles)
// blocks 672..799: Wq2 [1024x512] -> w2t [512][1024] bf16  (16 x 8 tiles)
// blocks 800..813: encoder pack (w1p f32 + w2e bf16)
__global__ __launch_bounds__(256) void prep_all(const float* __restrict__ Wq1, const float* __restrict__ Wq2,
                                                const float* __restrict__ Wp1, const float* __restrict__ bp1,
                                                const float* __restrict__ Wp2, const float* __restrict__ bp2,
                                                const float* __restrict__ Wt1, const float* __restrict__ bt1,
                                                const float* __restrict__ Wt2, const float* __restrict__ bt2,
                                                const float* __restrict__ Wr1, const float* __restrict__ br1,
                                                const float* __restrict__ Wr2, const float* __restrict__ br2,
                                                __bf16* __restrict__ w1t, __bf16* __restrict__ w2t,
                                                float* __restrict__ w1p, __bf16* __restrict__ w2e) {
    __shared__ float t[64][65];
    const int idx = blockIdx.x, tid = threadIdx.x;
    if (idx < 800) {
        const float* in; __bf16* out; int R, C, bx, by;
        if (idx < 672) { in = Wq1; out = w1t; R = 2688; C = 1024; bx = idx % 42; by = idx / 42; }
        else { const int i2 = idx - 672; in = Wq2; out = w2t; R = 1024; C = 512; bx = i2 % 16; by = i2 / 16; }
        const int r0 = bx * 64, c0 = by * 64;
#pragma unroll
        for (int i = 0; i < 16; i++) {
            int id2 = i * 256 + tid;
            int rr = id2 >> 6, cc = id2 & 63;
            t[rr][cc] = in[(size_t)(r0 + rr) * C + (c0 + cc)];
        }
        __syncthreads();
#pragma unroll
        for (int i = 0; i < 16; i++) {
            int id2 = i * 256 + tid;
            int rr = id2 >> 6, cc = id2 & 63;
            out[(size_t)(c0 + rr) * R + (r0 + cc)] = (__bf16)t[cc][rr];
        }
    } else {
        const int s = idx - 800;
        int ks, din, w1off;
        const float *W1, *B1, *W2, *B2;
        if (s < 9)      { ks = s;      din = 5;  w1off = s * 160;
                          W1 = Wp1; B1 = bp1; W2 = Wp2; B2 = bp2; }
        else if (s < 11){ ks = s - 9;  din = 12; w1off = 1440 + ks * 384;
                          W1 = Wt1; B1 = bt1; W2 = Wt2; B2 = bt2; }
        else            { ks = s - 11; din = 9;  w1off = 2208 + ks * 288;
                          W1 = Wr1; B1 = br1; W2 = Wr2; B2 = br2; }
        W1 += ks * din * 32; B1 += ks * 32; W2 += ks * 2048; B2 += ks * 64;
        for (int i = tid; i < din * 32; i += 256) w1p[w1off + i] = W1[i];
        if (tid < 32) w1p[3072 + s * 32 + tid] = B1[tid];
        if (tid < 64) w1p[3520 + s * 64 + tid] = B2[tid];
        for (int i = tid; i < 2048; i += 256) {
            const int o = i >> 5, k = i & 31;
            w2e[s * 2048 + i] = (__bf16)W2[k * 64 + o];
        }
    }
}

// ---------------- fused encoder v3: w2t prefetch pipeline + b128 stores via LDS ----------------
// 64 rows/block, 4 waves, 768 blocks (3/CU). One sync per segment. Per segment:
// sync | prefetch bfr(s+1) | store-out(s-1) via sO dbuf (2x b128/thread) |
// MFMA(s) with bfrA | bfrA<-bfrB | L1(s+1) into sH dbuf.
__global__ __launch_bounds__(256) void enc_fused(const float* __restrict__ obs,
                                                 const float* __restrict__ act,
                                                 const float* __restrict__ w1p,
                                                 const __bf16* __restrict__ w2t,
                                                 __bf16* __restrict__ enc) {
    __shared__ float sW[4416];                       // [3072 W1][448 b1][896 b2]
    __shared__ __bf16 sH[2][64 * 40];                // dbuf h tiles
    __shared__ __align__(16) __bf16 sO[2][64 * 72];  // dbuf out tiles (stride 72: 16B rows, 2-way write banks)
    const int tid = threadIdx.x;
    for (int i = tid; i < 4416; i += 256) sW[i] = w1p[i];
    const int rloc = tid >> 2, q = tid & 3;          // L1: row-in-block, h-quarter
    const int row = blockIdx.x * 64 + rloc;
    const float* orow = obs + (size_t)row * 144;
    const float a0 = act[row * 3], a1 = act[row * 3 + 1], a2 = act[row * 3 + 2];
    const int wv = tid >> 6, lane = tid & 63;
    const int fr = lane & 15, kq = lane >> 4;

    bf16x8 bfrA[4], bfrB[4];
    int curH = 0, curO = 0;

    auto prefetchB = [&](int sn) {
#pragma unroll
        for (int n = 0; n < 4; n++)
            bfrB[n] = *(const bf16x8*)&w2t[(sn * 64 + n * 16 + fr) * 32 + kq * 8];
    };
    auto storeOut = [&](int sp, int bO) {
#pragma unroll
        for (int h = 0; h < 2; h++) {
            const int c = tid + h * 256;
            const int r = c >> 3, ch = c & 7;
            const bf16x8 v = *(const bf16x8*)&sO[bO][r * 72 + ch * 8];
            *(bf16x8*)&enc[((size_t)blockIdx.x * 64 + r) * 896 + sp * 64 + ch * 8] = v;
        }
    };
    auto l2c = [&](int s, int bH, int bO) {
        const bf16x8 afr = *(const bf16x8*)&sH[bH][(wv * 16 + fr) * 40 + kq * 8];
        f32x4 acc[4] = {};
#pragma unroll
        for (int n = 0; n < 4; n++)
            acc[n] = __builtin_amdgcn_mfma_f32_16x16x32_bf16(afr, bfrA[n], acc[n], 0, 0, 0);
        const float* b2 = sW + 3520 + s * 64;
#pragma unroll
        for (int n = 0; n < 4; n++) {
            const float bv = b2[n * 16 + fr];
#pragma unroll
            for (int rg = 0; rg < 4; rg++) {
                float v = acc[n][rg] + bv;
                v = fmaxf(v, 0.01f * v);
                sO[bO][(wv * 16 + kq * 4 + rg) * 72 + n * 16 + fr] = (__bf16)v;
            }
        }
    };

#define L1(DIN, W1OFF, SGI, DH, XLOAD)                               \
    {                                                                \
        float x[DIN];                                                \
        XLOAD;                                                       \
        const float* w1 = sW + (W1OFF);                              \
        const float* b1 = sW + 3072 + (SGI) * 32;                    \
        bf16x8 t_;                                                   \
        _Pragma("unroll") for (int j = 0; j < 8; j++) {              \
            const int o = q * 8 + j;                                 \
            float a_ = b1[o];                                        \
            _Pragma("unroll") for (int i = 0; i < DIN; i++)          \
                a_ += x[i] * w1[i * 32 + o];                         \
            t_[j] = (__bf16)fmaxf(a_, 0.01f * a_);                   \
        }                                                            \
        *(bf16x8*)&sH[DH][rloc * 40 + q * 8] = t_;                   \
    }

#define PROPX(K) { x[0] = orow[2 * (K)]; x[1] = orow[2 * (K) + 1]; x[2] = a0; x[3] = a1; x[4] = a2; }
#define TEAMX(K) { _Pragma("unroll") for (int i = 0; i < 12; i++) x[i] = orow[18 + 12 * (K) + i]; }
#define RIVX(K)  { _Pragma("unroll") for (int i = 0; i < 9; i++) x[i] = orow[117 + 9 * (K) + i]; }

#define STEP(S, NEXTL1)                                              \
    __syncthreads();                                                 \
    if ((S) < 13) prefetchB((S) + 1);                                \
    if ((S) > 0) storeOut((S) - 1, curO ^ 1);                        \
    l2c((S), curH, curO);                                            \
    _Pragma("unroll") for (int n = 0; n < 4; n++) bfrA[n] = bfrB[n]; \
    NEXTL1                                                           \
    curH ^= 1; curO ^= 1;

    // prologue: bfr(0), L1(0) -> sH[0]  (sync inside STEP(0) covers sW fill too? No —
    // L1(0) reads sW, so sync BEFORE L1(0).)
    prefetchB(0);
    __syncthreads();                 // sW ready
#pragma unroll
    for (int n = 0; n < 4; n++) bfrA[n] = bfrB[n];
    L1(5, 0, 0, 0, PROPX(0))

    STEP(0,  L1(5, 160, 1, curH ^ 1, PROPX(1)))
    STEP(1,  L1(5, 320, 2, curH ^ 1, PROPX(2)))
    STEP(2,  L1(5, 480, 3, curH ^ 1, PROPX(3)))
    STEP(3,  L1(5, 640, 4, curH ^ 1, PROPX(4)))
    STEP(4,  L1(5, 800, 5, curH ^ 1, PROPX(5)))
    STEP(5,  L1(5, 960, 6, curH ^ 1, PROPX(6)))
    STEP(6,  L1(5, 1120, 7, curH ^ 1, PROPX(7)))
    STEP(7,  L1(5, 1280, 8, curH ^ 1, PROPX(8)))
    STEP(8,  L1(12, 1440, 9, curH ^ 1, TEAMX(0)))
    STEP(9,  L1(12, 1824, 10, curH ^ 1, TEAMX(1)))
    STEP(10, L1(9, 2208, 11, curH ^ 1, RIVX(0)))
    STEP(11, L1(9, 2496, 12, curH ^ 1, RIVX(1)))
    STEP(12, L1(9, 2784, 13, curH ^ 1, RIVX(2)))
    STEP(13, )

    __syncthreads();
    storeOut(13, curO ^ 1);
#undef STEP
#undef L1
#undef PROPX
#undef TEAMX
#undef RIVX
}

// ---------------- 256xBN bf16 GEMM: counted-vmcnt pipeline (R8 schedule, validated) ----------------
// Cross-wave rule: every ds_read of a staged region follows a BARRIER that is preceded
// (in ALL waves) by a vmcnt wait covering that region's loads.
//   W1: stage A0',B0'; vmcnt(4|3)  -> covers A1(t)   [read at W2, after W1.BAR]
//   W2: stage B1',A1'; (no wait)
//   W4: vmcnt(2)                   -> covers A0',B0' [read at W4 after BAR] and B1'
//                                     [read at next W1, after W4.BAR]
// One barrier per phase (NOT two): with 1 block/CU the inter-wave phase drift is the
// only MFMA/LDS overlap source — end-barriers cost ~12% (measured R9).
template <int NB>
__global__ __launch_bounds__(512, 2) void gemm256_relu(const __bf16* __restrict__ Ag,
                                                       const __bf16* __restrict__ Btg,
                                                       const float* __restrict__ bias,
                                                       __bf16* __restrict__ Cg,
                                                       int N, int K, int lgn) {
    __shared__ __align__(16) __bf16 ldsA[2][2][128 * 64];
    __shared__ __align__(16) __bf16 ldsB[2][2][NB * 64 * 64];
    const int tid = threadIdx.x;
    const int wid = tid >> 6, lane = tid & 63;
    const int wm = wid >> 2, wn = wid & 3;
    const int fr = lane & 15, kq = lane >> 4;

    const int chunk = gridDim.x >> 3;
    const int wg = (blockIdx.x & 7) * chunk + (blockIdx.x >> 3);
    const int bn = wg & ((1 << lgn) - 1), bm = wg >> lgn;

    const int c0 = tid, c1 = tid + 512;
    const int r0 = c0 >> 3, s0 = (c0 & 7) ^ (r0 & 7);
    const int r1 = c1 >> 3, s1 = (c1 & 7) ^ (r1 & 7);
    const size_t aH = (size_t)128 * K;
    const size_t bH = (size_t)(NB * 64) * K;
    const __bf16* aB0 = Ag + (size_t)(bm * 256 + r0) * K + s0 * 8;
    const __bf16* aB1 = Ag + (size_t)(bm * 256 + r1) * K + s1 * 8;
    const __bf16* bB0 = Btg + (size_t)(bn * (NB * 128) + r0) * K + s0 * 8;
    const __bf16* bB1 = Btg + (size_t)(bn * (NB * 128) + r1) * K + s1 * 8;

    f32x4 acc[2][2][4][NB] = {};
    bf16x8 a0[4][2], a1[4][2], b0[NB][2], b1[NB][2];

#define STAGE_A(BUF, H, KO)                                   \
    do {                                                      \
        __bf16* d_ = &ldsA[BUF][H][0];                        \
        gld16(aB0 + (H)*aH + (KO), d_ + c0 * 8);              \
        gld16(aB1 + (H)*aH + (KO), d_ + c1 * 8);              \
    } while (0)
#define STAGE_B(BUF, H, KO)                                   \
    do {                                                      \
        __bf16* d_ = &ldsB[BUF][H][0];                        \
        gld16(bB0 + (H)*bH + (KO), d_ + c0 * 8);              \
        if constexpr (NB == 2) gld16(bB1 + (H)*bH + (KO), d_ + c1 * 8); \
    } while (0)

#define LDFA(BUF, H, ROW, KS) \
    (*(const bf16x8*)&ldsA[BUF][H][(ROW) * 64 + ((((KS)*4 + kq) ^ ((ROW)&7)) * 8)])
#define LDFB(BUF, H, ROW, KS) \
    (*(const bf16x8*)&ldsB[BUF][H][(ROW) * 64 + ((((KS)*4 + kq) ^ ((ROW)&7)) * 8)])

#define LOAD_A(BUF, H, DST)                                   \
    _Pragma("unroll") for (int m = 0; m < 4; m++)             \
        _Pragma("unroll") for (int ks = 0; ks < 2; ks++)      \
            DST[m][ks] = LDFA(BUF, H, wm * 64 + m * 16 + fr, ks);
#define LOAD_B(BUF, H, DST)                                   \
    _Pragma("unroll") for (int n = 0; n < NB; n++)            \
        _Pragma("unroll") for (int ks = 0; ks < 2; ks++)      \
            DST[n][ks] = LDFB(BUF, H, wn * (NB * 16) + n * 16 + fr, ks);

#define MM(Q, R, AR, BR)                                      \
    __builtin_amdgcn_s_setprio(1);                            \
    _Pragma("unroll") for (int ks = 0; ks < 2; ks++)          \
        _Pragma("unroll") for (int m = 0; m < 4; m++)         \
            _Pragma("unroll") for (int n = 0; n < NB; n++)    \
                acc[Q][R][m][n] = __builtin_amdgcn_mfma_f32_16x16x32_bf16( \
                    AR[m][ks], BR[n][ks], acc[Q][R][m][n], 0, 0, 0); \
    __builtin_amdgcn_s_setprio(0);

#define SB0 __builtin_amdgcn_sched_barrier(0)
#define BAR __builtin_amdgcn_s_barrier()
#define LGKM_B1                                               \
    if constexpr (NB == 2) asm volatile("s_waitcnt lgkmcnt(4)" ::: "memory"); \
    else asm volatile("s_waitcnt lgkmcnt(2)" ::: "memory");
#define LGKM(NSTR) asm volatile("s_waitcnt lgkmcnt(" NSTR ")" ::: "memory")
#define VMW(NSTR) asm volatile("s_waitcnt vmcnt(" NSTR ")" ::: "memory")
#define VMW2(N2, N1)                                          \
    if constexpr (NB == 2) VMW(#N2); else VMW(#N1);

    const int NT = K >> 6;

    // prologue: stage tile 0 (A0,B0,B1,A1); cover all but A1 (read at W2(0))
    STAGE_A(0, 0, 0);
    STAGE_B(0, 0, 0);
    STAGE_B(0, 1, 0);
    STAGE_A(0, 1, 0);
    VMW("2");
    BAR;
    LOAD_A(0, 0, a0)
    LOAD_B(0, 0, b0)
    SB0;

    for (int t = 0; t < NT - 1; ++t) {
        const int buf = t & 1, nb = buf ^ 1;
        const int kO = (t + 1) << 6;

        // W1: stage A0',B0'; vmcnt covers A1(t) (leaves A0',B0' in flight)
        STAGE_A(nb, 0, kO);
        STAGE_B(nb, 0, kO);
        VMW2(4, 3);
        LOAD_B(buf, 1, b1)        // B1(t): covered by W4(t-1) VMW("2") + BAR
        SB0;
        BAR;
        LGKM_B1;
        SB0;
        MM(0, 0, a0, b0)

        // W2: stage B1',A1'
        STAGE_B(nb, 1, kO);
        STAGE_A(nb, 1, kO);
        LOAD_A(buf, 1, a1)        // A1(t): covered by W1 VMW2(4,3) + BAR
        SB0;
        BAR;
        LGKM("8");
        SB0;
        MM(0, 1, a0, b1)

        // W3
        BAR;
        LGKM("0");
        SB0;
        MM(1, 0, a1, b0)

        // W4: cover A0',B0',B1' (leaves only A1' in flight)
        VMW("2");
        BAR;
        LOAD_A(nb, 0, a0)
        LOAD_B(nb, 0, b0)
        SB0;
        MM(1, 1, a1, b1)
    }

    // peeled last tile: drain remaining (A1 of last tile), nothing staged beyond
    {
        const int buf = (NT - 1) & 1;
        VMW("0");
        LOAD_B(buf, 1, b1)
        SB0;
        BAR;
        LGKM_B1;
        SB0;
        MM(0, 0, a0, b0)

        LOAD_A(buf, 1, a1)
        SB0;
        BAR;
        LGKM("8");
        SB0;
        MM(0, 1, a0, b1)

        BAR;
        LGKM("0");
        SB0;
        MM(1, 0, a1, b0)

        MM(1, 1, a1, b1)
    }

    const int cc = lane & 15, rr = (lane >> 4) << 2;
#pragma unroll
    for (int q = 0; q < 2; q++)
#pragma unroll
        for (int r2 = 0; r2 < 2; r2++)
#pragma unroll
            for (int m = 0; m < 4; m++)
#pragma unroll
                for (int n = 0; n < NB; n++) {
                    const int colG = bn * (NB * 128) + r2 * (NB * 64) + wn * (NB * 16) + n * 16 + cc;
                    const int rowG = bm * 256 + q * 128 + wm * 64 + m * 16 + rr;
                    const float bv = bias[colG];
#pragma unroll
                    for (int reg = 0; reg < 4; reg++) {
                        float v = acc[q][r2][m][n][reg] + bv;
                        v = fmaxf(v, 0.0f);
                        Cg[(size_t)(rowG + reg) * N + colG] = (__bf16)v;
                    }
                }
#undef STAGE_A
#undef STAGE_B
#undef LDFA
#undef LDFB
#undef LOAD_A
#undef LOAD_B
#undef MM
#undef SB0
#undef BAR
#undef LGKM_B1
#undef LGKM
#undef VMW
#undef VMW2
}

// ---------------- head: out[b,j] = h2[b,:] . Wq3[:,j] + bq3[j], j<3, K=512 ----------------
__global__ __launch_bounds__(256) void head_kernel(const __bf16* __restrict__ h2,
                                                   const float* __restrict__ Wq3,
                                                   const float* __restrict__ bq3,
                                                   float* __restrict__ out) {
    const int wave = threadIdx.x >> 6, lane = threadIdx.x & 63;
    const int row = blockIdx.x * 4 + wave;
    const bf16x8 hv = *(const bf16x8*)(h2 + (size_t)row * 512 + lane * 8);
    float s0 = 0.f, s1 = 0.f, s2 = 0.f;
#pragma unroll
    for (int i = 0; i < 8; i++) {
        const float hf = (float)hv[i];
        const int k = lane * 8 + i;
        s0 += hf * Wq3[k * 3 + 0];
        s1 += hf * Wq3[k * 3 + 1];
        s2 += hf * Wq3[k * 3 + 2];
    }
#pragma unroll
    for (int off = 32; off > 0; off >>= 1) {
        s0 += __shfl_xor(s0, off);
        s1 += __shfl_xor(s1, off);
        s2 += __shfl_xor(s2, off);
    }
    if (lane == 0) {
        float* o = out + (size_t)row * 3;
        o[0] = s0 + bq3[0];
        o[1] = s1 + bq3[1];
        o[2] = s2 + bq3[2];
    }
}

extern "C" void kernel_launch(void* const* d_in, const int* in_sizes, int n_in,
                              void* d_out, int out_size, void* d_ws, size_t ws_size,
                              hipStream_t stream) {
    const float* obs = (const float*)d_in[0];
    const float* act = (const float*)d_in[1];
    const float* Wp1 = (const float*)d_in[2];  const float* bp1 = (const float*)d_in[3];
    const float* Wp2 = (const float*)d_in[4];  const float* bp2 = (const float*)d_in[5];
    const float* Wt1 = (const float*)d_in[6];  const float* bt1 = (const float*)d_in[7];
    const float* Wt2 = (const float*)d_in[8];  const float* bt2 = (const float*)d_in[9];
    const float* Wr1 = (const float*)d_in[10]; const float* br1 = (const float*)d_in[11];
    const float* Wr2 = (const float*)d_in[12]; const float* br2 = (const float*)d_in[13];
    const float* Wq1 = (const float*)d_in[14]; const float* bq1 = (const float*)d_in[15];
    const float* Wq2 = (const float*)d_in[16]; const float* bq2 = (const float*)d_in[17];
    const float* Wq3 = (const float*)d_in[18]; const float* bq3 = (const float*)d_in[19];
    float* out = (float*)d_out;

    char* ws = (char*)d_ws;
    __bf16* enc = (__bf16*)(ws);                            // 88,080,384
    __bf16* h1  = (__bf16*)(ws + 88080384);                 // 33,554,432
    __bf16* h2  = (__bf16*)(ws + 88080384 + 33554432);      // 16,777,216
    __bf16* w1t = (__bf16*)(ws + 138412032);                // 5,505,024
    __bf16* w2t = (__bf16*)(ws + 143917056);                // 1,048,576
    float*  w1p = (float*)(ws + 144965632);                 // 17,664
    __bf16* w2e = (__bf16*)(ws + 144983296);                // 57,344

    // fused weight prep (2 transposes + encoder pack in one launch)
    prep_all<<<814, 256, 0, stream>>>(Wq1, Wq2, Wp1, bp1, Wp2, bp2, Wt1, bt1, Wt2, bt2,
                                      Wr1, br1, Wr2, br2, w1t, w2t, w1p, w2e);

    // fused encoders: 49152 rows, 64 rows/block, 768 blocks (3/CU)
    enc_fused<<<768, 256, 0, stream>>>(obs, act, w1p, w2e, enc);

    // q head
    gemm256_relu<2><<<dim3(256), 512, 0, stream>>>(enc, w1t, bq1, h1, 1024, 2688, 2);
    gemm256_relu<1><<<dim3(256), 512, 0, stream>>>(h1, w2t, bq2, h2, 512, 1024, 2);
    head_kernel<<<16384 / 4, 256, 0, stream>>>(h2, Wq3, bq3, out);
}

// Round 12
// 136.685 us; speedup vs baseline: 1.8169x; 1.0082x over previous
//
#include <hip/hip_runtime.h>
#include <hip/hip_bf16.h>
#include <cstdint>

typedef __bf16 bf16x8 __attribute__((ext_vector_type(8)));
typedef float f32x4 __attribute__((ext_vector_type(4)));

// ---------------- async global->LDS (16B per lane) ----------------
__device__ __forceinline__ void gld16(const __bf16* g, __bf16* lds) {
    __builtin_amdgcn_global_load_lds(
        (__attribute__((address_space(1))) void*)(uintptr_t)g,
        (__attribute__((address_space(3))) void*)(uint32_t)(uintptr_t)lds,
        16, 0, 0);
}

// ---------------- fused weight prep: T(Wq1), T(Wq2), encoder pack — one launch ----------------
__global__ __launch_bounds__(256) void prep_all(const float* __restrict__ Wq1, const float* __restrict__ Wq2,
                                                const float* __restrict__ Wp1, const float* __restrict__ bp1,
                                                const float* __restrict__ Wp2, const float* __restrict__ bp2,
                                                const float* __restrict__ Wt1, const float* __restrict__ bt1,
                                                const float* __restrict__ Wt2, const float* __restrict__ bt2,
                                                const float* __restrict__ Wr1, const float* __restrict__ br1,
                                                const float* __restrict__ Wr2, const float* __restrict__ br2,
                                                __bf16* __restrict__ w1t, __bf16* __restrict__ w2t,
                                                float* __restrict__ w1p, __bf16* __restrict__ w2e) {
    __shared__ float t[64][65];
    const int idx = blockIdx.x, tid = threadIdx.x;
    if (idx < 800) {
        const float* in; __bf16* out; int R, C, bx, by;
        if (idx < 672) { in = Wq1; out = w1t; R = 2688; C = 1024; bx = idx % 42; by = idx / 42; }
        else { const int i2 = idx - 672; in = Wq2; out = w2t; R = 1024; C = 512; bx = i2 % 16; by = i2 / 16; }
        const int r0 = bx * 64, c0 = by * 64;
#pragma unroll
        for (int i = 0; i < 16; i++) {
            int id2 = i * 256 + tid;
            int rr = id2 >> 6, cc = id2 & 63;
            t[rr][cc] = in[(size_t)(r0 + rr) * C + (c0 + cc)];
        }
        __syncthreads();
#pragma unroll
        for (int i = 0; i < 16; i++) {
            int id2 = i * 256 + tid;
            int rr = id2 >> 6, cc = id2 & 63;
            out[(size_t)(c0 + rr) * R + (r0 + cc)] = (__bf16)t[cc][rr];
        }
    } else {
        const int s = idx - 800;
        int ks, din, w1off;
        const float *W1, *B1, *W2, *B2;
        if (s < 9)      { ks = s;      din = 5;  w1off = s * 160;
                          W1 = Wp1; B1 = bp1; W2 = Wp2; B2 = bp2; }
        else if (s < 11){ ks = s - 9;  din = 12; w1off = 1440 + ks * 384;
                          W1 = Wt1; B1 = bt1; W2 = Wt2; B2 = bt2; }
        else            { ks = s - 11; din = 9;  w1off = 2208 + ks * 288;
                          W1 = Wr1; B1 = br1; W2 = Wr2; B2 = br2; }
        W1 += ks * din * 32; B1 += ks * 32; W2 += ks * 2048; B2 += ks * 64;
        for (int i = tid; i < din * 32; i += 256) w1p[w1off + i] = W1[i];
        if (tid < 32) w1p[3072 + s * 32 + tid] = B1[tid];
        if (tid < 64) w1p[3520 + s * 64 + tid] = B2[tid];
        for (int i = tid; i < 2048; i += 256) {
            const int o = i >> 5, k = i & 31;
            w2e[s * 2048 + i] = (__bf16)W2[k * 64 + o];
        }
    }
}

// ---------------- fused encoder v3: w2t prefetch pipeline + b128 stores via LDS ----------------
__global__ __launch_bounds__(256) void enc_fused(const float* __restrict__ obs,
                                                 const float* __restrict__ act,
                                                 const float* __restrict__ w1p,
                                                 const __bf16* __restrict__ w2t,
                                                 __bf16* __restrict__ enc) {
    __shared__ float sW[4416];
    __shared__ __bf16 sH[2][64 * 40];
    __shared__ __align__(16) __bf16 sO[2][64 * 72];
    const int tid = threadIdx.x;
    for (int i = tid; i < 4416; i += 256) sW[i] = w1p[i];
    const int rloc = tid >> 2, q = tid & 3;
    const int row = blockIdx.x * 64 + rloc;
    const float* orow = obs + (size_t)row * 144;
    const float a0 = act[row * 3], a1 = act[row * 3 + 1], a2 = act[row * 3 + 2];
    const int wv = tid >> 6, lane = tid & 63;
    const int fr = lane & 15, kq = lane >> 4;

    bf16x8 bfrA[4], bfrB[4];
    int curH = 0, curO = 0;

    auto prefetchB = [&](int sn) {
#pragma unroll
        for (int n = 0; n < 4; n++)
            bfrB[n] = *(const bf16x8*)&w2t[(sn * 64 + n * 16 + fr) * 32 + kq * 8];
    };
    auto storeOut = [&](int sp, int bO) {
#pragma unroll
        for (int h = 0; h < 2; h++) {
            const int c = tid + h * 256;
            const int r = c >> 3, ch = c & 7;
            const bf16x8 v = *(const bf16x8*)&sO[bO][r * 72 + ch * 8];
            *(bf16x8*)&enc[((size_t)blockIdx.x * 64 + r) * 896 + sp * 64 + ch * 8] = v;
        }
    };
    auto l2c = [&](int s, int bH, int bO) {
        const bf16x8 afr = *(const bf16x8*)&sH[bH][(wv * 16 + fr) * 40 + kq * 8];
        f32x4 acc[4] = {};
#pragma unroll
        for (int n = 0; n < 4; n++)
            acc[n] = __builtin_amdgcn_mfma_f32_16x16x32_bf16(afr, bfrA[n], acc[n], 0, 0, 0);
        const float* b2 = sW + 3520 + s * 64;
#pragma unroll
        for (int n = 0; n < 4; n++) {
            const float bv = b2[n * 16 + fr];
#pragma unroll
            for (int rg = 0; rg < 4; rg++) {
                float v = acc[n][rg] + bv;
                v = fmaxf(v, 0.01f * v);
                sO[bO][(wv * 16 + kq * 4 + rg) * 72 + n * 16 + fr] = (__bf16)v;
            }
        }
    };

#define L1(DIN, W1OFF, SGI, DH, XLOAD)                               \
    {                                                                \
        float x[DIN];                                                \
        XLOAD;                                                       \
        const float* w1 = sW + (W1OFF);                              \
        const float* b1 = sW + 3072 + (SGI) * 32;                    \
        bf16x8 t_;                                                   \
        _Pragma("unroll") for (int j = 0; j < 8; j++) {              \
            const int o = q * 8 + j;                                 \
            float a_ = b1[o];                                        \
            _Pragma("unroll") for (int i = 0; i < DIN; i++)          \
                a_ += x[i] * w1[i * 32 + o];                         \
            t_[j] = (__bf16)fmaxf(a_, 0.01f * a_);                   \
        }                                                            \
        *(bf16x8*)&sH[DH][rloc * 40 + q * 8] = t_;                   \
    }

#define PROPX(K) { x[0] = orow[2 * (K)]; x[1] = orow[2 * (K) + 1]; x[2] = a0; x[3] = a1; x[4] = a2; }
#define TEAMX(K) { _Pragma("unroll") for (int i = 0; i < 12; i++) x[i] = orow[18 + 12 * (K) + i]; }
#define RIVX(K)  { _Pragma("unroll") for (int i = 0; i < 9; i++) x[i] = orow[117 + 9 * (K) + i]; }

#define STEP(S, NEXTL1)                                              \
    __syncthreads();                                                 \
    if ((S) < 13) prefetchB((S) + 1);                                \
    if ((S) > 0) storeOut((S) - 1, curO ^ 1);                        \
    l2c((S), curH, curO);                                            \
    _Pragma("unroll") for (int n = 0; n < 4; n++) bfrA[n] = bfrB[n]; \
    NEXTL1                                                           \
    curH ^= 1; curO ^= 1;

    prefetchB(0);
    __syncthreads();
#pragma unroll
    for (int n = 0; n < 4; n++) bfrA[n] = bfrB[n];
    L1(5, 0, 0, 0, PROPX(0))

    STEP(0,  L1(5, 160, 1, curH ^ 1, PROPX(1)))
    STEP(1,  L1(5, 320, 2, curH ^ 1, PROPX(2)))
    STEP(2,  L1(5, 480, 3, curH ^ 1, PROPX(3)))
    STEP(3,  L1(5, 640, 4, curH ^ 1, PROPX(4)))
    STEP(4,  L1(5, 800, 5, curH ^ 1, PROPX(5)))
    STEP(5,  L1(5, 960, 6, curH ^ 1, PROPX(6)))
    STEP(6,  L1(5, 1120, 7, curH ^ 1, PROPX(7)))
    STEP(7,  L1(5, 1280, 8, curH ^ 1, PROPX(8)))
    STEP(8,  L1(12, 1440, 9, curH ^ 1, TEAMX(0)))
    STEP(9,  L1(12, 1824, 10, curH ^ 1, TEAMX(1)))
    STEP(10, L1(9, 2208, 11, curH ^ 1, RIVX(0)))
    STEP(11, L1(9, 2496, 12, curH ^ 1, RIVX(1)))
    STEP(12, L1(9, 2784, 13, curH ^ 1, RIVX(2)))
    STEP(13, )

    __syncthreads();
    storeOut(13, curO ^ 1);
#undef STEP
#undef L1
#undef PROPX
#undef TEAMX
#undef RIVX
}

// ---------------- 256xBN bf16 GEMM: counted-vmcnt pipeline (R8 schedule, validated) ----------------
// K-loop identical to R8 (76 µs / 51% MfmaUtil). One barrier per phase — end-barriers
// cost ~12% at 1 block/CU (measured R9). HEAD=true: instead of writing C, fuse the
// 512->3 head: stage relu'd tile in (dead) ldsA with slot-XOR layout, per-row partial
// dot with Wq3, deterministic per-bn partials to pout[row][4][3] (no atomics).
template <int NB, bool HEAD>
__global__ __launch_bounds__(512, 2) void gemm256_relu(const __bf16* __restrict__ Ag,
                                                       const __bf16* __restrict__ Btg,
                                                       const float* __restrict__ bias,
                                                       __bf16* __restrict__ Cg,
                                                       const float* __restrict__ Wq3,
                                                       float* __restrict__ pout,
                                                       int N, int K, int lgn) {
    __shared__ __align__(16) __bf16 ldsF[32768 + 2 * 2 * NB * 4096];
    const int tid = threadIdx.x;
    const int wid = tid >> 6, lane = tid & 63;
    const int wm = wid >> 2, wn = wid & 3;
    const int fr = lane & 15, kq = lane >> 4;

    const int chunk = gridDim.x >> 3;
    const int wg = (blockIdx.x & 7) * chunk + (blockIdx.x >> 3);
    const int bn = wg & ((1 << lgn) - 1), bm = wg >> lgn;

    const int c0 = tid, c1 = tid + 512;
    const int r0 = c0 >> 3, s0 = (c0 & 7) ^ (r0 & 7);
    const int r1 = c1 >> 3, s1 = (c1 & 7) ^ (r1 & 7);
    const size_t aH = (size_t)128 * K;
    const size_t bH = (size_t)(NB * 64) * K;
    const __bf16* aB0 = Ag + (size_t)(bm * 256 + r0) * K + s0 * 8;
    const __bf16* aB1 = Ag + (size_t)(bm * 256 + r1) * K + s1 * 8;
    const __bf16* bB0 = Btg + (size_t)(bn * (NB * 128) + r0) * K + s0 * 8;
    const __bf16* bB1 = Btg + (size_t)(bn * (NB * 128) + r1) * K + s1 * 8;

    f32x4 acc[2][2][4][NB] = {};
    bf16x8 a0[4][2], a1[4][2], b0[NB][2], b1[NB][2];

#define LDSA(BUF, H) (ldsF + ((BUF) * 2 + (H)) * 8192)
#define LDSB(BUF, H) (ldsF + 32768 + ((BUF) * 2 + (H)) * (NB * 4096))

#define STAGE_A(BUF, H, KO)                                   \
    do {                                                      \
        __bf16* d_ = LDSA(BUF, H);                            \
        gld16(aB0 + (H)*aH + (KO), d_ + c0 * 8);              \
        gld16(aB1 + (H)*aH + (KO), d_ + c1 * 8);              \
    } while (0)
#define STAGE_B(BUF, H, KO)                                   \
    do {                                                      \
        __bf16* d_ = LDSB(BUF, H);                            \
        gld16(bB0 + (H)*bH + (KO), d_ + c0 * 8);              \
        if constexpr (NB == 2) gld16(bB1 + (H)*bH + (KO), d_ + c1 * 8); \
    } while (0)

#define LDFA(BUF, H, ROW, KS) \
    (*(const bf16x8*)&LDSA(BUF, H)[(ROW) * 64 + ((((KS)*4 + kq) ^ ((ROW)&7)) * 8)])
#define LDFB(BUF, H, ROW, KS) \
    (*(const bf16x8*)&LDSB(BUF, H)[(ROW) * 64 + ((((KS)*4 + kq) ^ ((ROW)&7)) * 8)])

#define LOAD_A(BUF, H, DST)                                   \
    _Pragma("unroll") for (int m = 0; m < 4; m++)             \
        _Pragma("unroll") for (int ks = 0; ks < 2; ks++)      \
            DST[m][ks] = LDFA(BUF, H, wm * 64 + m * 16 + fr, ks);
#define LOAD_B(BUF, H, DST)                                   \
    _Pragma("unroll") for (int n = 0; n < NB; n++)            \
        _Pragma("unroll") for (int ks = 0; ks < 2; ks++)      \
            DST[n][ks] = LDFB(BUF, H, wn * (NB * 16) + n * 16 + fr, ks);

#define MM(Q, R, AR, BR)                                      \
    __builtin_amdgcn_s_setprio(1);                            \
    _Pragma("unroll") for (int ks = 0; ks < 2; ks++)          \
        _Pragma("unroll") for (int m = 0; m < 4; m++)         \
            _Pragma("unroll") for (int n = 0; n < NB; n++)    \
                acc[Q][R][m][n] = __builtin_amdgcn_mfma_f32_16x16x32_bf16( \
                    AR[m][ks], BR[n][ks], acc[Q][R][m][n], 0, 0, 0); \
    __builtin_amdgcn_s_setprio(0);

#define SB0 __builtin_amdgcn_sched_barrier(0)
#define BAR __builtin_amdgcn_s_barrier()
#define LGKM_B1                                               \
    if constexpr (NB == 2) asm volatile("s_waitcnt lgkmcnt(4)" ::: "memory"); \
    else asm volatile("s_waitcnt lgkmcnt(2)" ::: "memory");
#define LGKM(NSTR) asm volatile("s_waitcnt lgkmcnt(" NSTR ")" ::: "memory")
#define VMW(NSTR) asm volatile("s_waitcnt vmcnt(" NSTR ")" ::: "memory")
#define VMW2(N2, N1)                                          \
    if constexpr (NB == 2) VMW(#N2); else VMW(#N1);

    const int NT = K >> 6;

    STAGE_A(0, 0, 0);
    STAGE_B(0, 0, 0);
    STAGE_B(0, 1, 0);
    STAGE_A(0, 1, 0);
    VMW("2");
    BAR;
    LOAD_A(0, 0, a0)
    LOAD_B(0, 0, b0)
    SB0;

    for (int t = 0; t < NT - 1; ++t) {
        const int buf = t & 1, nb = buf ^ 1;
        const int kO = (t + 1) << 6;

        // W1: stage A0',B0'; vmcnt covers A1(t)
        STAGE_A(nb, 0, kO);
        STAGE_B(nb, 0, kO);
        VMW2(4, 3);
        LOAD_B(buf, 1, b1)
        SB0;
        BAR;
        LGKM_B1;
        SB0;
        MM(0, 0, a0, b0)

        // W2: stage B1',A1'
        STAGE_B(nb, 1, kO);
        STAGE_A(nb, 1, kO);
        LOAD_A(buf, 1, a1)
        SB0;
        BAR;
        LGKM("8");
        SB0;
        MM(0, 1, a0, b1)

        // W3
        BAR;
        LGKM("0");
        SB0;
        MM(1, 0, a1, b0)

        // W4: cover A0',B0',B1' (leaves only A1' in flight)
        VMW("2");
        BAR;
        LOAD_A(nb, 0, a0)
        LOAD_B(nb, 0, b0)
        SB0;
        MM(1, 1, a1, b1)
    }

    {
        const int buf = (NT - 1) & 1;
        VMW("0");
        LOAD_B(buf, 1, b1)
        SB0;
        BAR;
        LGKM_B1;
        SB0;
        MM(0, 0, a0, b0)

        LOAD_A(buf, 1, a1)
        SB0;
        BAR;
        LGKM("8");
        SB0;
        MM(0, 1, a0, b1)

        BAR;
        LGKM("0");
        SB0;
        MM(1, 0, a1, b0)

        MM(1, 1, a1, b1)
    }

    const int cc = lane & 15, rr = (lane >> 4) << 2;
    if constexpr (!HEAD) {
#pragma unroll
        for (int q = 0; q < 2; q++)
#pragma unroll
            for (int r2 = 0; r2 < 2; r2++)
#pragma unroll
                for (int m = 0; m < 4; m++)
#pragma unroll
                    for (int n = 0; n < NB; n++) {
                        const int colG = bn * (NB * 128) + r2 * (NB * 64) + wn * (NB * 16) + n * 16 + cc;
                        const int rowG = bm * 256 + q * 128 + wm * 64 + m * 16 + rr;
                        const float bv = bias[colG];
#pragma unroll
                        for (int reg = 0; reg < 4; reg++) {
                            float v = acc[q][r2][m][n][reg] + bv;
                            v = fmaxf(v, 0.0f);
                            Cg[(size_t)(rowG + reg) * N + colG] = (__bf16)v;
                        }
                    }
    } else {
        // fused head epilogue (NB==1): hS[256][16 slots of 8], phys slot = logical ^ (row&7)
        __syncthreads();   // all waves done with LDS (lgkm drained per-wave, vm drained at peel)
        __bf16* hS = ldsF;
#pragma unroll
        for (int q = 0; q < 2; q++)
#pragma unroll
            for (int r2 = 0; r2 < 2; r2++)
#pragma unroll
                for (int m = 0; m < 4; m++) {
                    const int colL = r2 * 64 + wn * 16 + cc;
                    const int rowL0 = q * 128 + wm * 64 + m * 16 + rr;
                    const float bv = bias[bn * 128 + colL];
                    const int slot = colL >> 3, pos = colL & 7;
#pragma unroll
                    for (int reg = 0; reg < 4; reg++) {
                        const int rowL = rowL0 + reg;
                        float v = acc[q][r2][m][0][reg] + bv;
                        v = fmaxf(v, 0.0f);
                        hS[rowL * 128 + (slot ^ (rowL & 7)) * 8 + pos] = (__bf16)v;
                    }
                }
        __syncthreads();
        const int rowL = tid >> 1, half = tid & 1;
        float s0 = 0.f, s1 = 0.f, s2 = 0.f;
#pragma unroll
        for (int c8 = 0; c8 < 8; c8++) {
            const int lslot = half * 8 + c8;
            const int pslot = half * 8 + (c8 ^ (rowL & 7));
            const bf16x8 hv = *(const bf16x8*)&hS[rowL * 128 + pslot * 8];
#pragma unroll
            for (int j = 0; j < 8; j++) {
                const float hf = (float)hv[j];
                const int col = bn * 128 + lslot * 8 + j;
                s0 += hf * Wq3[col * 3 + 0];
                s1 += hf * Wq3[col * 3 + 1];
                s2 += hf * Wq3[col * 3 + 2];
            }
        }
        s0 += __shfl_xor(s0, 1);
        s1 += __shfl_xor(s1, 1);
        s2 += __shfl_xor(s2, 1);
        if (!half) {
            float* p = pout + ((size_t)(bm * 256 + rowL) * 4 + bn) * 3;
            p[0] = s0; p[1] = s1; p[2] = s2;
        }
    }
#undef LDSA
#undef LDSB
#undef STAGE_A
#undef STAGE_B
#undef LDFA
#undef LDFB
#undef LOAD_A
#undef LOAD_B
#undef MM
#undef SB0
#undef BAR
#undef LGKM_B1
#undef LGKM
#undef VMW
#undef VMW2
}

// ---------------- reduce: out[row][j] = sum_bn pout[row][bn][j] + bq3[j] ----------------
__global__ __launch_bounds__(256) void reduce_head(const float* __restrict__ pout,
                                                   const float* __restrict__ bq3,
                                                   float* __restrict__ out) {
    const int row = blockIdx.x * 256 + threadIdx.x;
    const float* p = pout + (size_t)row * 12;
#pragma unroll
    for (int j = 0; j < 3; j++)
        out[(size_t)row * 3 + j] = p[j] + p[3 + j] + p[6 + j] + p[9 + j] + bq3[j];
}

extern "C" void kernel_launch(void* const* d_in, const int* in_sizes, int n_in,
                              void* d_out, int out_size, void* d_ws, size_t ws_size,
                              hipStream_t stream) {
    const float* obs = (const float*)d_in[0];
    const float* act = (const float*)d_in[1];
    const float* Wp1 = (const float*)d_in[2];  const float* bp1 = (const float*)d_in[3];
    const float* Wp2 = (const float*)d_in[4];  const float* bp2 = (const float*)d_in[5];
    const float* Wt1 = (const float*)d_in[6];  const float* bt1 = (const float*)d_in[7];
    const float* Wt2 = (const float*)d_in[8];  const float* bt2 = (const float*)d_in[9];
    const float* Wr1 = (const float*)d_in[10]; const float* br1 = (const float*)d_in[11];
    const float* Wr2 = (const float*)d_in[12]; const float* br2 = (const float*)d_in[13];
    const float* Wq1 = (const float*)d_in[14]; const float* bq1 = (const float*)d_in[15];
    const float* Wq2 = (const float*)d_in[16]; const float* bq2 = (const float*)d_in[17];
    const float* Wq3 = (const float*)d_in[18]; const float* bq3 = (const float*)d_in[19];
    float* out = (float*)d_out;

    char* ws = (char*)d_ws;
    __bf16* enc  = (__bf16*)(ws);                            // 88,080,384
    __bf16* h1   = (__bf16*)(ws + 88080384);                 // 33,554,432
    float*  pout = (float*)(ws + 88080384 + 33554432);       // 786,432 (h2's old slot)
    __bf16* w1t  = (__bf16*)(ws + 138412032);                // 5,505,024
    __bf16* w2t  = (__bf16*)(ws + 143917056);                // 1,048,576
    float*  w1p  = (float*)(ws + 144965632);                 // 17,664
    __bf16* w2e  = (__bf16*)(ws + 144983296);                // 57,344

    // fused weight prep (2 transposes + encoder pack in one launch)
    prep_all<<<814, 256, 0, stream>>>(Wq1, Wq2, Wp1, bp1, Wp2, bp2, Wt1, bt1, Wt2, bt2,
                                      Wr1, br1, Wr2, br2, w1t, w2t, w1p, w2e);

    // fused encoders: 49152 rows, 64 rows/block, 768 blocks (3/CU)
    enc_fused<<<768, 256, 0, stream>>>(obs, act, w1p, w2e, enc);

    // q head: GEMM1 (C-writing), GEMM2 (fused head partials), reduce
    gemm256_relu<2, false><<<dim3(256), 512, 0, stream>>>(enc, w1t, bq1, h1, nullptr, nullptr, 1024, 2688, 2);
    gemm256_relu<1, true><<<dim3(256), 512, 0, stream>>>(h1, w2t, bq2, nullptr, Wq3, pout, 512, 1024, 2);
    reduce_head<<<64, 256, 0, stream>>>(pout, bq3, out);
}

// Round 13
// 135.268 us; speedup vs baseline: 1.8359x; 1.0105x over previous
//
#include <hip/hip_runtime.h>
#include <hip/hip_bf16.h>
#include <cstdint>

typedef __bf16 bf16x8 __attribute__((ext_vector_type(8)));
typedef float f32x4 __attribute__((ext_vector_type(4)));

// ---------------- async global->LDS (16B per lane) ----------------
__device__ __forceinline__ void gld16(const __bf16* g, __bf16* lds) {
    __builtin_amdgcn_global_load_lds(
        (__attribute__((address_space(1))) void*)(uintptr_t)g,
        (__attribute__((address_space(3))) void*)(uint32_t)(uintptr_t)lds,
        16, 0, 0);
}

// ---------------- fused weight prep: T(Wq1), T(Wq2), encoder pack — one launch ----------------
__global__ __launch_bounds__(256) void prep_all(const float* __restrict__ Wq1, const float* __restrict__ Wq2,
                                                const float* __restrict__ Wp1, const float* __restrict__ bp1,
                                                const float* __restrict__ Wp2, const float* __restrict__ bp2,
                                                const float* __restrict__ Wt1, const float* __restrict__ bt1,
                                                const float* __restrict__ Wt2, const float* __restrict__ bt2,
                                                const float* __restrict__ Wr1, const float* __restrict__ br1,
                                                const float* __restrict__ Wr2, const float* __restrict__ br2,
                                                __bf16* __restrict__ w1t, __bf16* __restrict__ w2t,
                                                float* __restrict__ w1p, __bf16* __restrict__ w2e) {
    __shared__ float t[64][65];
    const int idx = blockIdx.x, tid = threadIdx.x;
    if (idx < 800) {
        const float* in; __bf16* out; int R, C, bx, by;
        if (idx < 672) { in = Wq1; out = w1t; R = 2688; C = 1024; bx = idx % 42; by = idx / 42; }
        else { const int i2 = idx - 672; in = Wq2; out = w2t; R = 1024; C = 512; bx = i2 % 16; by = i2 / 16; }
        const int r0 = bx * 64, c0 = by * 64;
#pragma unroll
        for (int i = 0; i < 16; i++) {
            int id2 = i * 256 + tid;
            int rr = id2 >> 6, cc = id2 & 63;
            t[rr][cc] = in[(size_t)(r0 + rr) * C + (c0 + cc)];
        }
        __syncthreads();
#pragma unroll
        for (int i = 0; i < 16; i++) {
            int id2 = i * 256 + tid;
            int rr = id2 >> 6, cc = id2 & 63;
            out[(size_t)(c0 + rr) * R + (r0 + cc)] = (__bf16)t[cc][rr];
        }
    } else {
        const int s = idx - 800;
        int ks, din, w1off;
        const float *W1, *B1, *W2, *B2;
        if (s < 9)      { ks = s;      din = 5;  w1off = s * 160;
                          W1 = Wp1; B1 = bp1; W2 = Wp2; B2 = bp2; }
        else if (s < 11){ ks = s - 9;  din = 12; w1off = 1440 + ks * 384;
                          W1 = Wt1; B1 = bt1; W2 = Wt2; B2 = bt2; }
        else            { ks = s - 11; din = 9;  w1off = 2208 + ks * 288;
                          W1 = Wr1; B1 = br1; W2 = Wr2; B2 = br2; }
        W1 += ks * din * 32; B1 += ks * 32; W2 += ks * 2048; B2 += ks * 64;
        for (int i = tid; i < din * 32; i += 256) w1p[w1off + i] = W1[i];
        if (tid < 32) w1p[3072 + s * 32 + tid] = B1[tid];
        if (tid < 64) w1p[3520 + s * 64 + tid] = B2[tid];
        for (int i = tid; i < 2048; i += 256) {
            const int o = i >> 5, k = i & 31;
            w2e[s * 2048 + i] = (__bf16)W2[k * 64 + o];
        }
    }
}

// ---------------- fused encoder v3: w2t prefetch pipeline + b128 stores via LDS ----------------
__global__ __launch_bounds__(256) void enc_fused(const float* __restrict__ obs,
                                                 const float* __restrict__ act,
                                                 const float* __restrict__ w1p,
                                                 const __bf16* __restrict__ w2t,
                                                 __bf16* __restrict__ enc) {
    __shared__ float sW[4416];
    __shared__ __bf16 sH[2][64 * 40];
    __shared__ __align__(16) __bf16 sO[2][64 * 72];
    const int tid = threadIdx.x;
    for (int i = tid; i < 4416; i += 256) sW[i] = w1p[i];
    const int rloc = tid >> 2, q = tid & 3;
    const int row = blockIdx.x * 64 + rloc;
    const float* orow = obs + (size_t)row * 144;
    const float a0 = act[row * 3], a1 = act[row * 3 + 1], a2 = act[row * 3 + 2];
    const int wv = tid >> 6, lane = tid & 63;
    const int fr = lane & 15, kq = lane >> 4;

    bf16x8 bfrA[4], bfrB[4];
    int curH = 0, curO = 0;

    auto prefetchB = [&](int sn) {
#pragma unroll
        for (int n = 0; n < 4; n++)
            bfrB[n] = *(const bf16x8*)&w2t[(sn * 64 + n * 16 + fr) * 32 + kq * 8];
    };
    auto storeOut = [&](int sp, int bO) {
#pragma unroll
        for (int h = 0; h < 2; h++) {
            const int c = tid + h * 256;
            const int r = c >> 3, ch = c & 7;
            const bf16x8 v = *(const bf16x8*)&sO[bO][r * 72 + ch * 8];
            *(bf16x8*)&enc[((size_t)blockIdx.x * 64 + r) * 896 + sp * 64 + ch * 8] = v;
        }
    };
    auto l2c = [&](int s, int bH, int bO) {
        const bf16x8 afr = *(const bf16x8*)&sH[bH][(wv * 16 + fr) * 40 + kq * 8];
        f32x4 acc[4] = {};
#pragma unroll
        for (int n = 0; n < 4; n++)
            acc[n] = __builtin_amdgcn_mfma_f32_16x16x32_bf16(afr, bfrA[n], acc[n], 0, 0, 0);
        const float* b2 = sW + 3520 + s * 64;
#pragma unroll
        for (int n = 0; n < 4; n++) {
            const float bv = b2[n * 16 + fr];
#pragma unroll
            for (int rg = 0; rg < 4; rg++) {
                float v = acc[n][rg] + bv;
                v = fmaxf(v, 0.01f * v);
                sO[bO][(wv * 16 + kq * 4 + rg) * 72 + n * 16 + fr] = (__bf16)v;
            }
        }
    };

#define L1(DIN, W1OFF, SGI, DH, XLOAD)                               \
    {                                                                \
        float x[DIN];                                                \
        XLOAD;                                                       \
        const float* w1 = sW + (W1OFF);                              \
        const float* b1 = sW + 3072 + (SGI) * 32;                    \
        bf16x8 t_;                                                   \
        _Pragma("unroll") for (int j = 0; j < 8; j++) {              \
            const int o = q * 8 + j;                                 \
            float a_ = b1[o];                                        \
            _Pragma("unroll") for (int i = 0; i < DIN; i++)          \
                a_ += x[i] * w1[i * 32 + o];                         \
            t_[j] = (__bf16)fmaxf(a_, 0.01f * a_);                   \
        }                                                            \
        *(bf16x8*)&sH[DH][rloc * 40 + q * 8] = t_;                   \
    }

#define PROPX(K) { x[0] = orow[2 * (K)]; x[1] = orow[2 * (K) + 1]; x[2] = a0; x[3] = a1; x[4] = a2; }
#define TEAMX(K) { _Pragma("unroll") for (int i = 0; i < 12; i++) x[i] = orow[18 + 12 * (K) + i]; }
#define RIVX(K)  { _Pragma("unroll") for (int i = 0; i < 9; i++) x[i] = orow[117 + 9 * (K) + i]; }

#define STEP(S, NEXTL1)                                              \
    __syncthreads();                                                 \
    if ((S) < 13) prefetchB((S) + 1);                                \
    if ((S) > 0) storeOut((S) - 1, curO ^ 1);                        \
    l2c((S), curH, curO);                                            \
    _Pragma("unroll") for (int n = 0; n < 4; n++) bfrA[n] = bfrB[n]; \
    NEXTL1                                                           \
    curH ^= 1; curO ^= 1;

    prefetchB(0);
    __syncthreads();
#pragma unroll
    for (int n = 0; n < 4; n++) bfrA[n] = bfrB[n];
    L1(5, 0, 0, 0, PROPX(0))

    STEP(0,  L1(5, 160, 1, curH ^ 1, PROPX(1)))
    STEP(1,  L1(5, 320, 2, curH ^ 1, PROPX(2)))
    STEP(2,  L1(5, 480, 3, curH ^ 1, PROPX(3)))
    STEP(3,  L1(5, 640, 4, curH ^ 1, PROPX(4)))
    STEP(4,  L1(5, 800, 5, curH ^ 1, PROPX(5)))
    STEP(5,  L1(5, 960, 6, curH ^ 1, PROPX(6)))
    STEP(6,  L1(5, 1120, 7, curH ^ 1, PROPX(7)))
    STEP(7,  L1(5, 1280, 8, curH ^ 1, PROPX(8)))
    STEP(8,  L1(12, 1440, 9, curH ^ 1, TEAMX(0)))
    STEP(9,  L1(12, 1824, 10, curH ^ 1, TEAMX(1)))
    STEP(10, L1(9, 2208, 11, curH ^ 1, RIVX(0)))
    STEP(11, L1(9, 2496, 12, curH ^ 1, RIVX(1)))
    STEP(12, L1(9, 2784, 13, curH ^ 1, RIVX(2)))
    STEP(13, )

    __syncthreads();
    storeOut(13, curO ^ 1);
#undef STEP
#undef L1
#undef PROPX
#undef TEAMX
#undef RIVX
}

// ---------------- 256xBN bf16 GEMM: single-barrier tile schedule ----------------
// One collective barrier per K-tile. Stages issued a full tile before the VMW(0)
// drain (~4000 cyc >> 900 cyc HBM latency -> drain nearly free). All fragment reads
// are within-tile (no cross-tile register carry). lgkm ledger (NB=2|NB=1):
//   issue a0(8),b0(4|2) | stage 8|6 | issue b1(4|2),a1(8)  -> outstanding 24|20
//   MM(0,0) after lgkm(12|10); MM(0,1) after lgkm(8); MM(1,0) after lgkm(0).
// Races: reads of buf(t) complete (consumed) before BAR(t+1); stages into nb issued
// only after BAR(t); nb's prior reads (tile t-1) drained before BAR(t). Max wave
// drift = 1 tile -> cross-wave MFMA/LDS overlap (the R9 lesson inverted).
template <int NB, bool HEAD>
__global__ __launch_bounds__(512, 2) void gemm256_relu(const __bf16* __restrict__ Ag,
                                                       const __bf16* __restrict__ Btg,
                                                       const float* __restrict__ bias,
                                                       __bf16* __restrict__ Cg,
                                                       const float* __restrict__ Wq3,
                                                       float* __restrict__ pout,
                                                       int N, int K, int lgn) {
    __shared__ __align__(16) __bf16 ldsF[32768 + 2 * 2 * NB * 4096];
    const int tid = threadIdx.x;
    const int wid = tid >> 6, lane = tid & 63;
    const int wm = wid >> 2, wn = wid & 3;
    const int fr = lane & 15, kq = lane >> 4;

    const int chunk = gridDim.x >> 3;
    const int wg = (blockIdx.x & 7) * chunk + (blockIdx.x >> 3);
    const int bn = wg & ((1 << lgn) - 1), bm = wg >> lgn;

    const int c0 = tid, c1 = tid + 512;
    const int r0 = c0 >> 3, s0 = (c0 & 7) ^ (r0 & 7);
    const int r1 = c1 >> 3, s1 = (c1 & 7) ^ (r1 & 7);
    const size_t aH = (size_t)128 * K;
    const size_t bH = (size_t)(NB * 64) * K;
    const __bf16* aB0 = Ag + (size_t)(bm * 256 + r0) * K + s0 * 8;
    const __bf16* aB1 = Ag + (size_t)(bm * 256 + r1) * K + s1 * 8;
    const __bf16* bB0 = Btg + (size_t)(bn * (NB * 128) + r0) * K + s0 * 8;
    const __bf16* bB1 = Btg + (size_t)(bn * (NB * 128) + r1) * K + s1 * 8;

    f32x4 acc[2][2][4][NB] = {};
    bf16x8 a0[4][2], a1[4][2], b0[NB][2], b1[NB][2];

#define LDSA(BUF, H) (ldsF + ((BUF) * 2 + (H)) * 8192)
#define LDSB(BUF, H) (ldsF + 32768 + ((BUF) * 2 + (H)) * (NB * 4096))

#define STAGE_A(BUF, H, KO)                                   \
    do {                                                      \
        __bf16* d_ = LDSA(BUF, H);                            \
        gld16(aB0 + (H)*aH + (KO), d_ + c0 * 8);              \
        gld16(aB1 + (H)*aH + (KO), d_ + c1 * 8);              \
    } while (0)
#define STAGE_B(BUF, H, KO)                                   \
    do {                                                      \
        __bf16* d_ = LDSB(BUF, H);                            \
        gld16(bB0 + (H)*bH + (KO), d_ + c0 * 8);              \
        if constexpr (NB == 2) gld16(bB1 + (H)*bH + (KO), d_ + c1 * 8); \
    } while (0)

#define LDFA(BUF, H, ROW, KS) \
    (*(const bf16x8*)&LDSA(BUF, H)[(ROW) * 64 + ((((KS)*4 + kq) ^ ((ROW)&7)) * 8)])
#define LDFB(BUF, H, ROW, KS) \
    (*(const bf16x8*)&LDSB(BUF, H)[(ROW) * 64 + ((((KS)*4 + kq) ^ ((ROW)&7)) * 8)])

#define LOAD_A(BUF, H, DST)                                   \
    _Pragma("unroll") for (int m = 0; m < 4; m++)             \
        _Pragma("unroll") for (int ks = 0; ks < 2; ks++)      \
            DST[m][ks] = LDFA(BUF, H, wm * 64 + m * 16 + fr, ks);
#define LOAD_B(BUF, H, DST)                                   \
    _Pragma("unroll") for (int n = 0; n < NB; n++)            \
        _Pragma("unroll") for (int ks = 0; ks < 2; ks++)      \
            DST[n][ks] = LDFB(BUF, H, wn * (NB * 16) + n * 16 + fr, ks);

#define MM(Q, R, AR, BR)                                      \
    __builtin_amdgcn_s_setprio(1);                            \
    _Pragma("unroll") for (int ks = 0; ks < 2; ks++)          \
        _Pragma("unroll") for (int m = 0; m < 4; m++)         \
            _Pragma("unroll") for (int n = 0; n < NB; n++)    \
                acc[Q][R][m][n] = __builtin_amdgcn_mfma_f32_16x16x32_bf16( \
                    AR[m][ks], BR[n][ks], acc[Q][R][m][n], 0, 0, 0); \
    __builtin_amdgcn_s_setprio(0);

#define SB0 __builtin_amdgcn_sched_barrier(0)
#define BAR __builtin_amdgcn_s_barrier()
#define LGKM(NSTR) asm volatile("s_waitcnt lgkmcnt(" NSTR ")" ::: "memory")
#define LGKM2(N2, N1)                                         \
    if constexpr (NB == 2) LGKM(#N2); else LGKM(#N1);
#define VMW(NSTR) asm volatile("s_waitcnt vmcnt(" NSTR ")" ::: "memory")

    const int NT = K >> 6;

    // prologue: stage tile 0 (loop-top VMW(0)+BAR covers it)
    STAGE_A(0, 0, 0);
    STAGE_B(0, 0, 0);
    STAGE_B(0, 1, 0);
    STAGE_A(0, 1, 0);

    for (int t = 0; t < NT; ++t) {
        const int buf = t & 1, nb = buf ^ 1;
        const int kO = (t + 1) << 6;

        VMW("0");                 // stages for buf landed (issued 1 tile ago)
        BAR;
        // reads needed first
        LOAD_A(buf, 0, a0)
        LOAD_B(buf, 0, b0)
        SB0;
        // stage next tile into the other buffer
        if (t + 1 < NT) {
            STAGE_A(nb, 0, kO);
            STAGE_B(nb, 0, kO);
            STAGE_B(nb, 1, kO);
            STAGE_A(nb, 1, kO);
        }
        SB0;
        // remaining reads (in flight during MM(0,0)/MM(0,1))
        LOAD_B(buf, 1, b1)
        LOAD_A(buf, 1, a1)
        SB0;
        LGKM2(12, 10);            // a0,b0 done
        SB0;
        MM(0, 0, a0, b0)
        LGKM("8");                // b1 done
        SB0;
        MM(0, 1, a0, b1)
        LGKM("0");                // a1 done
        SB0;
        MM(1, 0, a1, b0)
        MM(1, 1, a1, b1)
    }

    const int cc = lane & 15, rr = (lane >> 4) << 2;
    if constexpr (!HEAD) {
#pragma unroll
        for (int q = 0; q < 2; q++)
#pragma unroll
            for (int r2 = 0; r2 < 2; r2++)
#pragma unroll
                for (int m = 0; m < 4; m++)
#pragma unroll
                    for (int n = 0; n < NB; n++) {
                        const int colG = bn * (NB * 128) + r2 * (NB * 64) + wn * (NB * 16) + n * 16 + cc;
                        const int rowG = bm * 256 + q * 128 + wm * 64 + m * 16 + rr;
                        const float bv = bias[colG];
#pragma unroll
                        for (int reg = 0; reg < 4; reg++) {
                            float v = acc[q][r2][m][n][reg] + bv;
                            v = fmaxf(v, 0.0f);
                            Cg[(size_t)(rowG + reg) * N + colG] = (__bf16)v;
                        }
                    }
    } else {
        // fused head epilogue (NB==1): hS[256 rows][16 slots of 8], phys slot = logical ^ (row&7)
        __syncthreads();
        __bf16* hS = ldsF;
#pragma unroll
        for (int q = 0; q < 2; q++)
#pragma unroll
            for (int r2 = 0; r2 < 2; r2++)
#pragma unroll
                for (int m = 0; m < 4; m++) {
                    const int colL = r2 * 64 + wn * 16 + cc;
                    const int rowL0 = q * 128 + wm * 64 + m * 16 + rr;
                    const float bv = bias[bn * 128 + colL];
                    const int slot = colL >> 3, pos = colL & 7;
#pragma unroll
                    for (int reg = 0; reg < 4; reg++) {
                        const int rowL = rowL0 + reg;
                        float v = acc[q][r2][m][0][reg] + bv;
                        v = fmaxf(v, 0.0f);
                        hS[rowL * 128 + (slot ^ (rowL & 7)) * 8 + pos] = (__bf16)v;
                    }
                }
        __syncthreads();
        const int rowL = tid >> 1, half = tid & 1;
        float s0 = 0.f, s1 = 0.f, s2 = 0.f;
#pragma unroll
        for (int c8 = 0; c8 < 8; c8++) {
            const int lslot = half * 8 + c8;
            const int pslot = half * 8 + (c8 ^ (rowL & 7));
            const bf16x8 hv = *(const bf16x8*)&hS[rowL * 128 + pslot * 8];
#pragma unroll
            for (int j = 0; j < 8; j++) {
                const float hf = (float)hv[j];
                const int col = bn * 128 + lslot * 8 + j;
                s0 += hf * Wq3[col * 3 + 0];
                s1 += hf * Wq3[col * 3 + 1];
                s2 += hf * Wq3[col * 3 + 2];
            }
        }
        s0 += __shfl_xor(s0, 1);
        s1 += __shfl_xor(s1, 1);
        s2 += __shfl_xor(s2, 1);
        if (!half) {
            float* p = pout + ((size_t)(bm * 256 + rowL) * 4 + bn) * 3;
            p[0] = s0; p[1] = s1; p[2] = s2;
        }
    }
#undef LDSA
#undef LDSB
#undef STAGE_A
#undef STAGE_B
#undef LDFA
#undef LDFB
#undef LOAD_A
#undef LOAD_B
#undef MM
#undef SB0
#undef BAR
#undef LGKM
#undef LGKM2
#undef VMW
}

// ---------------- reduce: out[row][j] = sum_bn pout[row][bn][j] + bq3[j] ----------------
__global__ __launch_bounds__(256) void reduce_head(const float* __restrict__ pout,
                                                   const float* __restrict__ bq3,
                                                   float* __restrict__ out) {
    const int row = blockIdx.x * 256 + threadIdx.x;
    const float* p = pout + (size_t)row * 12;
#pragma unroll
    for (int j = 0; j < 3; j++)
        out[(size_t)row * 3 + j] = p[j] + p[3 + j] + p[6 + j] + p[9 + j] + bq3[j];
}

extern "C" void kernel_launch(void* const* d_in, const int* in_sizes, int n_in,
                              void* d_out, int out_size, void* d_ws, size_t ws_size,
                              hipStream_t stream) {
    const float* obs = (const float*)d_in[0];
    const float* act = (const float*)d_in[1];
    const float* Wp1 = (const float*)d_in[2];  const float* bp1 = (const float*)d_in[3];
    const float* Wp2 = (const float*)d_in[4];  const float* bp2 = (const float*)d_in[5];
    const float* Wt1 = (const float*)d_in[6];  const float* bt1 = (const float*)d_in[7];
    const float* Wt2 = (const float*)d_in[8];  const float* bt2 = (const float*)d_in[9];
    const float* Wr1 = (const float*)d_in[10]; const float* br1 = (const float*)d_in[11];
    const float* Wr2 = (const float*)d_in[12]; const float* br2 = (const float*)d_in[13];
    const float* Wq1 = (const float*)d_in[14]; const float* bq1 = (const float*)d_in[15];
    const float* Wq2 = (const float*)d_in[16]; const float* bq2 = (const float*)d_in[17];
    const float* Wq3 = (const float*)d_in[18]; const float* bq3 = (const float*)d_in[19];
    float* out = (float*)d_out;

    char* ws = (char*)d_ws;
    __bf16* enc  = (__bf16*)(ws);                            // 88,080,384
    __bf16* h1   = (__bf16*)(ws + 88080384);                 // 33,554,432
    float*  pout = (float*)(ws + 88080384 + 33554432);       // 786,432
    __bf16* w1t  = (__bf16*)(ws + 138412032);                // 5,505,024
    __bf16* w2t  = (__bf16*)(ws + 143917056);                // 1,048,576
    float*  w1p  = (float*)(ws + 144965632);                 // 17,664
    __bf16* w2e  = (__bf16*)(ws + 144983296);                // 57,344

    // fused weight prep (2 transposes + encoder pack in one launch)
    prep_all<<<814, 256, 0, stream>>>(Wq1, Wq2, Wp1, bp1, Wp2, bp2, Wt1, bt1, Wt2, bt2,
                                      Wr1, br1, Wr2, br2, w1t, w2t, w1p, w2e);

    // fused encoders: 49152 rows, 64 rows/block, 768 blocks (3/CU)
    enc_fused<<<768, 256, 0, stream>>>(obs, act, w1p, w2e, enc);

    // q head: GEMM1 (C-writing), GEMM2 (fused head partials), reduce
    gemm256_relu<2, false><<<dim3(256), 512, 0, stream>>>(enc, w1t, bq1, h1, nullptr, nullptr, 1024, 2688, 2);
    gemm256_relu<1, true><<<dim3(256), 512, 0, stream>>>(h1, w2t, bq2, nullptr, Wq3, pout, 512, 1024, 2);
    reduce_head<<<64, 256, 0, stream>>>(pout, bq3, out);
}